// Round 2
// baseline (142.380 us; speedup 1.0000x reference)
//
#include <hip/hip_runtime.h>
#include <hip/hip_bf16.h>

// RelationNet fused pipeline, fp32 in/out — TWO dispatches.
// B=4 Q=256 S=128 C=256; feats 512 -> 256 -> 64 -> 1; BN (training) + ReLU each layer.
//
// Factorization: concat(uq,us)@W0^T = query@W0a^T + support@W0b^T => Aq[b,q,o], As[b,s,o]
// (b0 folded into As). BN0 stats analytic from per-b sums. GEMM0 ~fp32 via 3-term
// in-register hi/lo bf16 split (D1). BN0 finalize redundant per block in D2.
//
// R16: D2 = GEMM1 + BN1 + layer2 + BN2 + out, all fused. y1 NEVER leaves registers
// (kept as packed bf16, bit-identical rounding to the old stored path) — the old
// y1f 16 MB write + 16 MB read is gone. Only BN1 partials (2 KB) and BN2 partials
// (128 B) cross blocks, via cache-bypassing spread atomicAdd. Grid sync = fence-free
// counter barrier: __syncthreads drains vmcnt (atomics committed at coherence point
// before the RELAXED counter add); spin + re-reads are RELAXED agent-scope atomic
// loads (no buffer_inv / wbl2 — R15 showed ACQ_REL fencing cost ~ a dispatch floor).
// Deadlock-safe: 512 blocks @ __launch_bounds__(256,2) => 2 blocks/CU co-resident
// (LDS 38 KB allows 4/CU); counters zeroed by D1 blk384 every launch/replay.

typedef __attribute__((ext_vector_type(4))) float f32x4;
typedef __attribute__((ext_vector_type(8))) short s16x8;

#define BN_EPS 1e-5f
#define INV_N  (1.0f/131072.0f)

__device__ __forceinline__ unsigned pk_bf16(float a, float b) {
  float2 t; t.x = a; t.y = b;
  __hip_bfloat162 h = __float22bfloat162_rn(t);
  return *reinterpret_cast<unsigned*>(&h);  // low16 = bf16(a), high16 = bf16(b)
}
__device__ __forceinline__ void split2(float a, float b, unsigned& uh, unsigned& ul) {
  uh = pk_bf16(a, b);
  float ha = __uint_as_float(uh << 16);
  float hb = __uint_as_float(uh & 0xFFFF0000u);
  ul = pk_bf16(a - ha, b - hb);
}

union frag_u { s16x8 v; unsigned u[4]; };

struct Args {
  const float *Sf, *Qf, *W0, *b0, *g0, *bt0, *W1, *b1, *g1, *bt1, *W2, *b2, *g2, *bt2;
  float *Aq, *As, *ws0s, *ws1f, *ws2f, *out;
  unsigned *cnt;   // [0]=barrier A, [1]=barrier B
};

// ---------------------------------------------------------------------------
// D1: GEMM0. 385 blocks x 64 thr (one 16x64 wave-tile each). chunk = bi>>2
// (0..63 Aq, 64..95 As), ntile = bi&3. W0 split in-register (3-term).
// BN0 partial slots (no atomics): ws0s[chunk*512 + o] / [..+256+o].
// Block 384: zero ws1f/ws2f atomic pads + both barrier counters.
// ---------------------------------------------------------------------------
__global__ __launch_bounds__(64) void k_g0(Args a)
{
  int bi = blockIdx.x, t = threadIdx.x;
  if (bi == 384) {
    for (int i = t; i < 2048; i += 64) a.ws1f[i] = 0.0f;
    if (t < 32) a.ws2f[t] = 0.0f;
    if (t < 2)  a.cnt[t] = 0u;
    return;
  }
  int l15 = t & 15, quad = t >> 4;
  int chunk = bi >> 2, ntile = bi & 3;
  bool isQ = (chunk < 64);
  const float* X; float* Out; int m0, koff;
  if (isQ) { m0 = chunk * 16; X = a.Qf; Out = a.Aq; koff = 0; }
  else     { m0 = (chunk - 64) * 16; X = a.Sf; Out = a.As; koff = 256; }
  int n0 = ntile * 64;

  f32x4 acc[4] = {};
#pragma unroll
  for (int ko = 0; ko < 256; ko += 32) {
    const float* row = X + (m0 + l15) * 256 + ko + quad * 8;
    f32x4 v0 = *(const f32x4*)(row);
    f32x4 v1 = *(const f32x4*)(row + 4);
    frag_u ah, al;
#pragma unroll
    for (int j = 0; j < 2; j++) {
      split2(v0[2 * j], v0[2 * j + 1], ah.u[j], al.u[j]);
      split2(v1[2 * j], v1[2 * j + 1], ah.u[2 + j], al.u[2 + j]);
    }
#pragma unroll
    for (int nt = 0; nt < 4; nt++) {
      const float* wrow = a.W0 + (n0 + nt * 16 + l15) * 512 + koff + ko + quad * 8;
      f32x4 w0v = *(const f32x4*)(wrow);
      f32x4 w1v = *(const f32x4*)(wrow + 4);
      frag_u bh, bl;
      split2(w0v[0], w0v[1], bh.u[0], bl.u[0]);
      split2(w0v[2], w0v[3], bh.u[1], bl.u[1]);
      split2(w1v[0], w1v[1], bh.u[2], bl.u[2]);
      split2(w1v[2], w1v[3], bh.u[3], bl.u[3]);
      acc[nt] = __builtin_amdgcn_mfma_f32_16x16x32_bf16(ah.v, bh.v, acc[nt], 0, 0, 0);
      acc[nt] = __builtin_amdgcn_mfma_f32_16x16x32_bf16(al.v, bh.v, acc[nt], 0, 0, 0);
      acc[nt] = __builtin_amdgcn_mfma_f32_16x16x32_bf16(ah.v, bl.v, acc[nt], 0, 0, 0);
    }
  }
  // D: col = l15 (o-in-tile), row = quad*4 + r
#pragma unroll
  for (int nt = 0; nt < 4; nt++) {
    int o = n0 + nt * 16 + l15;
    float bias = isQ ? 0.0f : a.b0[o];
    float cs = 0, cs2 = 0;
#pragma unroll
    for (int r = 0; r < 4; r++) {
      float y = acc[nt][r] + bias;
      Out[(m0 + quad * 4 + r) * 256 + o] = y;
      cs += y; cs2 += y * y;
    }
    cs  += __shfl_xor(cs, 16);  cs  += __shfl_xor(cs, 32);
    cs2 += __shfl_xor(cs2, 16); cs2 += __shfl_xor(cs2, 32);
    if (quad == 0) {
      a.ws0s[chunk * 512 + o] = cs;
      a.ws0s[chunk * 512 + 256 + o] = cs2;
    }
  }
}

// Redundant per-block BN0 finalize from D1's slots -> LDS a0/c0.
__device__ __forceinline__ void bn0_finalize(const Args& a, int t, float* sh_a0c0)
{
  int o = t;
  float sumY = 0, cross = 0, SQ2 = 0, SS2 = 0;
#pragma unroll
  for (int b = 0; b < 4; b++) {
    float sq1 = 0, sq2 = 0, ss1 = 0, ss2 = 0;
#pragma unroll
    for (int c = 0; c < 16; c++) {
      sq1 += a.ws0s[(b * 16 + c) * 512 + o];
      sq2 += a.ws0s[(b * 16 + c) * 512 + 256 + o];
    }
#pragma unroll
    for (int c = 0; c < 8; c++) {
      ss1 += a.ws0s[(64 + b * 8 + c) * 512 + o];
      ss2 += a.ws0s[(64 + b * 8 + c) * 512 + 256 + o];
    }
    SQ2 += sq2; SS2 += ss2;
    sumY += 128.0f * sq1 + 256.0f * ss1;
    cross += sq1 * ss1;
  }
  float mean = sumY * INV_N;
  float var = (128.0f * SQ2 + 256.0f * SS2 + 2.0f * cross) * INV_N - mean * mean;
  float aa = a.g0[o] * rsqrtf(var + BN_EPS);
  sh_a0c0[o] = aa;
  sh_a0c0[256 + o] = a.bt0[o] - mean * aa;
}

// Fence-free co-resident-grid barrier. __syncthreads drains each wave's vmcnt
// (compiler emits s_waitcnt vmcnt(0) before s_barrier), so all prior device-scope
// atomicAdds are committed at the coherence point before the counter bump.
// RELAXED ops only — no buffer_inv/wbl2 (R15: ACQ_REL cost ~ a dispatch floor).
__device__ __forceinline__ void grid_barrier(unsigned* cnt, unsigned target, int t)
{
  asm volatile("s_waitcnt vmcnt(0)" ::: "memory");
  __syncthreads();
  if (t == 0) {
    __hip_atomic_fetch_add(cnt, 1u, __ATOMIC_RELAXED, __HIP_MEMORY_SCOPE_AGENT);
    while (__hip_atomic_load(cnt, __ATOMIC_RELAXED, __HIP_MEMORY_SCOPE_AGENT) < target)
      __builtin_amdgcn_s_sleep(8);
  }
  __syncthreads();
}

// ---------------------------------------------------------------------------
// D2: fully fused GEMM1 + BN1 + layer2 + BN2 + out. 512 blocks x 256 thr,
// __launch_bounds__(256,2) => 2 blocks/CU, all co-resident (barrier-safe).
// Per block: one (b,qt,st) tile (16 q x 16 s x 64 j). y1 stays in registers
// as packed bf16 (ku01/ku23), bit-identical to the old stored-y1f path.
// ---------------------------------------------------------------------------
__global__ __launch_bounds__(256, 2) void k_f(Args a)
{
  int bi = blockIdx.x, t = threadIdx.x;
  int w = t >> 6, l = t & 63, l15 = l & 15, quad = l >> 4;
  __shared__ ushort w1f[2048 * 8];    // 32 KB, frag order
  __shared__ float sh_a0c0[512];
  __shared__ float red[2][4][4][16];
  __shared__ float sh_tot[128];
  __shared__ float sh_a1c1[128];
  __shared__ float rs[16], rs2[16];
  __shared__ float sh_fin[2];

  // stage W1 (fp32) -> LDS bf16 frag order
#pragma unroll
  for (int i = 0; i < 8; i++) {
    int fr = i * 256 + t;
    int kk = fr >> 8, r = fr & 255, nt = r >> 6, ln = r & 63;
    const float* src = a.W1 + (nt * 16 + (ln & 15)) * 256 + kk * 32 + (ln >> 4) * 8;
    f32x4 v0 = *(const f32x4*)(src);
    f32x4 v1 = *(const f32x4*)(src + 4);
    frag_u z;
    z.u[0] = pk_bf16(v0[0], v0[1]); z.u[1] = pk_bf16(v0[2], v0[3]);
    z.u[2] = pk_bf16(v1[0], v1[1]); z.u[3] = pk_bf16(v1[2], v1[3]);
    *(s16x8*)(w1f + fr * 8) = z.v;
  }
  bn0_finalize(a, t, sh_a0c0);
  __syncthreads();

  int b_ = bi >> 7, rem = bi & 127, qt = rem >> 3, st = rem & 7;
  const float* asrow = a.As + ((b_ << 7) + st * 16 + l15) * 256;
  const float* aqrow[4];
#pragma unroll
  for (int mt = 0; mt < 4; mt++)
    aqrow[mt] = a.Aq + ((b_ << 8) + qt * 16 + w * 4 + mt) * 256;

  f32x4 acc[4][4] = {};
#pragma unroll
  for (int kk = 0; kk < 8; kk++) {
    int obase = kk * 32 + quad * 8;
    f32x4 a0v0 = *(const f32x4*)(sh_a0c0 + obase);
    f32x4 a0v1 = *(const f32x4*)(sh_a0c0 + obase + 4);
    f32x4 c0v0 = *(const f32x4*)(sh_a0c0 + 256 + obase);
    f32x4 c0v1 = *(const f32x4*)(sh_a0c0 + 256 + obase + 4);
    f32x4 as0 = *(const f32x4*)(asrow + obase);
    f32x4 as1 = *(const f32x4*)(asrow + obase + 4);

    s16x8 zh[4];
#pragma unroll
    for (int mt = 0; mt < 4; mt++) {
      f32x4 aq0 = *(const f32x4*)(aqrow[mt] + obase);
      f32x4 aq1 = *(const f32x4*)(aqrow[mt] + obase + 4);
      f32x4 z0 = (aq0 + as0) * a0v0 + c0v0;
      f32x4 z1 = (aq1 + as1) * a0v1 + c0v1;
      frag_u zz;
      zz.u[0] = pk_bf16(fmaxf(z0[0], 0.0f), fmaxf(z0[1], 0.0f));
      zz.u[1] = pk_bf16(fmaxf(z0[2], 0.0f), fmaxf(z0[3], 0.0f));
      zz.u[2] = pk_bf16(fmaxf(z1[0], 0.0f), fmaxf(z1[1], 0.0f));
      zz.u[3] = pk_bf16(fmaxf(z1[2], 0.0f), fmaxf(z1[3], 0.0f));
      zh[mt] = zz.v;
    }
#pragma unroll
    for (int nt = 0; nt < 4; nt++) {
      s16x8 bw = *(const s16x8*)(w1f + ((kk * 4 + nt) * 64 + l) * 8);
#pragma unroll
      for (int mt = 0; mt < 4; mt++)
        acc[mt][nt] = __builtin_amdgcn_mfma_f32_16x16x32_bf16(zh[mt], bw, acc[mt][nt], 0, 0, 0);
    }
  }

  // epilogue: add bias, bf16-round, KEEP y1 in registers; stats from rounded values
  float biasv[4];
#pragma unroll
  for (int nt = 0; nt < 4; nt++) biasv[nt] = a.b1[nt * 16 + l15];
  unsigned ku01[4][4], ku23[4][4];
  float s[4] = {0, 0, 0, 0}, s2[4] = {0, 0, 0, 0};
#pragma unroll
  for (int mt = 0; mt < 4; mt++) {
#pragma unroll
    for (int nt = 0; nt < 4; nt++) {
      float y0 = acc[mt][nt][0] + biasv[nt];
      float y1 = acc[mt][nt][1] + biasv[nt];
      float y2v = acc[mt][nt][2] + biasv[nt];
      float y3 = acc[mt][nt][3] + biasv[nt];
      unsigned u01 = pk_bf16(y0, y1), u23 = pk_bf16(y2v, y3);
      ku01[mt][nt] = u01; ku23[mt][nt] = u23;
      float f0 = __uint_as_float(u01 << 16), f1 = __uint_as_float(u01 & 0xFFFF0000u);
      float f2 = __uint_as_float(u23 << 16), f3 = __uint_as_float(u23 & 0xFFFF0000u);
      s[nt]  += f0 + f1 + f2 + f3;
      s2[nt] += f0 * f0 + f1 * f1 + f2 * f2 + f3 * f3;
    }
  }
#pragma unroll
  for (int nt = 0; nt < 4; nt++) {
    float v = s[nt], v2 = s2[nt];
    v  += __shfl_xor(v, 16);  v  += __shfl_xor(v, 32);
    v2 += __shfl_xor(v2, 16); v2 += __shfl_xor(v2, 32);
    if (quad == 0) { red[0][w][nt][l15] = v; red[1][w][nt][l15] = v2; }
  }
  __syncthreads();
  if (t < 128) {
    int which = t >> 6, j = t & 63, nt = j >> 4, jl = j & 15;
    float v = red[which][0][nt][jl] + red[which][1][nt][jl] +
              red[which][2][nt][jl] + red[which][3][nt][jl];
    atomicAdd(&a.ws1f[(bi & 15) * 128 + t], v);  // t<64: sum[j], t>=64: sumsq[j]
  }

  // ---- barrier A: BN1 partials visible ----
  grid_barrier(&a.cnt[0], 512u, t);

  // BN1 finalize (redundant per block) via cache-bypassing relaxed loads
  if (t < 128) {
    float accv = 0;
#pragma unroll
    for (int c = 0; c < 16; c++)
      accv += __hip_atomic_load(&a.ws1f[c * 128 + t], __ATOMIC_RELAXED, __HIP_MEMORY_SCOPE_AGENT);
    sh_tot[t] = accv;
  }
  __syncthreads();
  if (t < 64) {
    float mean = sh_tot[t] * INV_N;
    float var = sh_tot[64 + t] * INV_N - mean * mean;
    float aa = a.g1[t] * rsqrtf(var + BN_EPS);
    sh_a1c1[t] = aa;
    sh_a1c1[64 + t] = a.bt1[t] - mean * aa;
  }
  __syncthreads();

  // layer 2 from register-held y1: z1 = relu(a1*y1+c1); y2 = z1@W2 + b2
  float a1v[4], c1v[4], w2v[4];
#pragma unroll
  for (int nt = 0; nt < 4; nt++) {
    int j = nt * 16 + l15;
    a1v[nt] = sh_a1c1[j]; c1v[nt] = sh_a1c1[64 + j]; w2v[nt] = a.W2[j];
  }
  float b2v = a.b2[0];
  float y2k[4][4];
  float ls = 0, ls2 = 0;
#pragma unroll
  for (int mt = 0; mt < 4; mt++) {
    float part[4] = {0, 0, 0, 0};
#pragma unroll
    for (int nt = 0; nt < 4; nt++) {
      unsigned u01 = ku01[mt][nt], u23 = ku23[mt][nt];
      float f0 = __uint_as_float(u01 << 16), f1 = __uint_as_float(u01 & 0xFFFF0000u);
      float f2 = __uint_as_float(u23 << 16), f3 = __uint_as_float(u23 & 0xFFFF0000u);
      part[0] += fmaxf(a1v[nt] * f0 + c1v[nt], 0.0f) * w2v[nt];
      part[1] += fmaxf(a1v[nt] * f1 + c1v[nt], 0.0f) * w2v[nt];
      part[2] += fmaxf(a1v[nt] * f2 + c1v[nt], 0.0f) * w2v[nt];
      part[3] += fmaxf(a1v[nt] * f3 + c1v[nt], 0.0f) * w2v[nt];
    }
#pragma unroll
    for (int r = 0; r < 4; r++) {
      float pv = part[r];
      pv += __shfl_xor(pv, 1); pv += __shfl_xor(pv, 2);
      pv += __shfl_xor(pv, 4); pv += __shfl_xor(pv, 8);
      float y = pv + b2v;                    // full sum in all 16 j-lanes
      y2k[mt][r] = y;
      if (l15 == 0) { ls += y; ls2 += y * y; }
    }
  }
  if (l15 == 0) { rs[t >> 4] = ls; rs2[t >> 4] = ls2; }
  __syncthreads();
  if (t == 0) {
    float sv = 0, sv2 = 0;
#pragma unroll
    for (int i = 0; i < 16; i++) { sv += rs[i]; sv2 += rs2[i]; }
    atomicAdd(&a.ws2f[(bi & 15) * 2], sv);       // 32 adds/address, device scope
    atomicAdd(&a.ws2f[(bi & 15) * 2 + 1], sv2);
  }

  // ---- barrier B: BN2 partials visible ----
  grid_barrier(&a.cnt[1], 512u, t);

  if (t == 0) {
    float sv = 0, sv2 = 0;
#pragma unroll
    for (int c = 0; c < 16; c++) {
      sv  += __hip_atomic_load(&a.ws2f[c * 2],     __ATOMIC_RELAXED, __HIP_MEMORY_SCOPE_AGENT);
      sv2 += __hip_atomic_load(&a.ws2f[c * 2 + 1], __ATOMIC_RELAXED, __HIP_MEMORY_SCOPE_AGENT);
    }
    float mean = sv * INV_N;
    float var = sv2 * INV_N - mean * mean;
    float aa = a.g2[0] * rsqrtf(var + BN_EPS);
    sh_fin[0] = aa;
    sh_fin[1] = a.bt2[0] - mean * aa;
  }
  __syncthreads();
  float aav = sh_fin[0], ccv = sh_fin[1];

  // BN2 + ReLU on register-held y2; write out at true (b,q,s)
#pragma unroll
  for (int mt = 0; mt < 4; mt++) {
    if (l15 == 0) {
      int q = qt * 16 + w * 4 + mt;
      int P = ((b_ * 256 + q) * 128) + st * 16 + quad * 4;
      f32x4 o;
#pragma unroll
      for (int r = 0; r < 4; r++) o[r] = fmaxf(aav * y2k[mt][r] + ccv, 0.0f);
      *(f32x4*)(a.out + P) = o;
    }
  }
}

extern "C" void kernel_launch(void* const* d_in, const int* in_sizes, int n_in,
                              void* d_out, int out_size, void* d_ws, size_t ws_size,
                              hipStream_t stream)
{
  float* ws = (float*)d_ws;
  Args a;
  a.Sf  = (const float*)d_in[0];   // support [4,128,256]
  a.Qf  = (const float*)d_in[1];   // query   [4,256,256]
  a.W0  = (const float*)d_in[2];   // [256,512]
  a.b0  = (const float*)d_in[3];
  a.g0  = (const float*)d_in[4];
  a.bt0 = (const float*)d_in[5];
  a.W1  = (const float*)d_in[6];   // [64,256]
  a.b1  = (const float*)d_in[7];
  a.g1  = (const float*)d_in[8];
  a.bt1 = (const float*)d_in[9];
  a.W2  = (const float*)d_in[10];  // [1,64]
  a.b2  = (const float*)d_in[11];
  a.g2  = (const float*)d_in[12];
  a.bt2 = (const float*)d_in[13];

  a.Aq   = ws;                       // 262144 f
  a.As   = ws + 262144;              // 131072 f
  a.ws0s = ws + 524288;              // 96*512 = 49152 f (BN0 slots, fully overwritten)
  a.ws1f = ws + 573440;              // 2048 f (16-way spread atomics, zeroed by D1 blk384)
  a.ws2f = ws + 575488;              // 32 f   (16-way spread atomics, zeroed by D1 blk384)
  a.cnt  = (unsigned*)(ws + 575520); // 2 barrier counters (zeroed by D1 blk384)
  a.out  = (float*)d_out;            // total ws use ~2.3 MB

  k_g0<<<385, 64, 0, stream>>>(a);
  k_f <<<512, 256, 0, stream>>>(a);
}

// Round 3
// 128.835 us; speedup vs baseline: 1.1051x; 1.1051x over previous
//
#include <hip/hip_runtime.h>
#include <hip/hip_bf16.h>

// RelationNet fused pipeline, fp32 in/out — TWO dispatches.
// B=4 Q=256 S=128 C=256; feats 512 -> 256 -> 64 -> 1; BN (training) + ReLU each layer.
//
// Factorization: concat(uq,us)@W0^T = query@W0a^T + support@W0b^T => Aq[b,q,o], As[b,s,o]
// (b0 folded into As). BN0 stats analytic from per-b sums. GEMM0 ~fp32 via 3-term
// in-register hi/lo bf16 split (D1). BN0 finalize redundant per block in D2.
//
// R16: D2 = GEMM1 + BN1 + layer2 + BN2 + out fused; y1 register-resident (bf16-packed,
// bit-identical rounding); only BN1 (2 KB) / BN2 (128 B) partials cross blocks.
// R17: barrier v3. R16's flat barrier (512 pollers x 1 line x s_sleep(8)) saturated
// the coherence point (~2400 polls/us vs ~50/us service) — k_f was 60us with 80% idle.
// Now: tree arrival (16 leaf lines, 32 RMWs max per line -> 16-add root), 16 spread
// gate lines (32 pollers each), s_sleep(32) backoff with check-before-sleep.
// All RELAXED agent-scope (no buffer_inv/wbl2); visibility validated by R16 numerics.
// Deadlock-safe: 512 blocks @ __launch_bounds__(256,2), all co-resident; barrier
// words zeroed by D1 blk384 every launch/replay.

typedef __attribute__((ext_vector_type(4))) float f32x4;
typedef __attribute__((ext_vector_type(8))) short s16x8;

#define BN_EPS 1e-5f
#define INV_N  (1.0f/131072.0f)

__device__ __forceinline__ unsigned pk_bf16(float a, float b) {
  float2 t; t.x = a; t.y = b;
  __hip_bfloat162 h = __float22bfloat162_rn(t);
  return *reinterpret_cast<unsigned*>(&h);  // low16 = bf16(a), high16 = bf16(b)
}
__device__ __forceinline__ void split2(float a, float b, unsigned& uh, unsigned& ul) {
  uh = pk_bf16(a, b);
  float ha = __uint_as_float(uh << 16);
  float hb = __uint_as_float(uh & 0xFFFF0000u);
  ul = pk_bf16(a - ha, b - hb);
}

union frag_u { s16x8 v; unsigned u[4]; };

struct Args {
  const float *Sf, *Qf, *W0, *b0, *g0, *bt0, *W1, *b1, *g1, *bt1, *W2, *b2, *g2, *bt2;
  float *Aq, *As, *ws0s, *ws1f, *ws2f, *out;
  unsigned *cnt;   // 2 barriers x 528 u32 (16 leaf lines + root line + 16 gate lines)
};

// ---------------------------------------------------------------------------
// D1: GEMM0. 385 blocks x 64 thr (one 16x64 wave-tile each). chunk = bi>>2
// (0..63 Aq, 64..95 As), ntile = bi&3. W0 split in-register (3-term).
// BN0 partial slots (no atomics): ws0s[chunk*512 + o] / [..+256+o].
// Block 384: zero ws1f/ws2f atomic pads + both barrier areas.
// ---------------------------------------------------------------------------
__global__ __launch_bounds__(64) void k_g0(Args a)
{
  int bi = blockIdx.x, t = threadIdx.x;
  if (bi == 384) {
    for (int i = t; i < 2048; i += 64) a.ws1f[i] = 0.0f;
    if (t < 32) a.ws2f[t] = 0.0f;
    for (int i = t; i < 1056; i += 64) a.cnt[i] = 0u;
    return;
  }
  int l15 = t & 15, quad = t >> 4;
  int chunk = bi >> 2, ntile = bi & 3;
  bool isQ = (chunk < 64);
  const float* X; float* Out; int m0, koff;
  if (isQ) { m0 = chunk * 16; X = a.Qf; Out = a.Aq; koff = 0; }
  else     { m0 = (chunk - 64) * 16; X = a.Sf; Out = a.As; koff = 256; }
  int n0 = ntile * 64;

  f32x4 acc[4] = {};
#pragma unroll
  for (int ko = 0; ko < 256; ko += 32) {
    const float* row = X + (m0 + l15) * 256 + ko + quad * 8;
    f32x4 v0 = *(const f32x4*)(row);
    f32x4 v1 = *(const f32x4*)(row + 4);
    frag_u ah, al;
#pragma unroll
    for (int j = 0; j < 2; j++) {
      split2(v0[2 * j], v0[2 * j + 1], ah.u[j], al.u[j]);
      split2(v1[2 * j], v1[2 * j + 1], ah.u[2 + j], al.u[2 + j]);
    }
#pragma unroll
    for (int nt = 0; nt < 4; nt++) {
      const float* wrow = a.W0 + (n0 + nt * 16 + l15) * 512 + koff + ko + quad * 8;
      f32x4 w0v = *(const f32x4*)(wrow);
      f32x4 w1v = *(const f32x4*)(wrow + 4);
      frag_u bh, bl;
      split2(w0v[0], w0v[1], bh.u[0], bl.u[0]);
      split2(w0v[2], w0v[3], bh.u[1], bl.u[1]);
      split2(w1v[0], w1v[1], bh.u[2], bl.u[2]);
      split2(w1v[2], w1v[3], bh.u[3], bl.u[3]);
      acc[nt] = __builtin_amdgcn_mfma_f32_16x16x32_bf16(ah.v, bh.v, acc[nt], 0, 0, 0);
      acc[nt] = __builtin_amdgcn_mfma_f32_16x16x32_bf16(al.v, bh.v, acc[nt], 0, 0, 0);
      acc[nt] = __builtin_amdgcn_mfma_f32_16x16x32_bf16(ah.v, bl.v, acc[nt], 0, 0, 0);
    }
  }
  // D: col = l15 (o-in-tile), row = quad*4 + r
#pragma unroll
  for (int nt = 0; nt < 4; nt++) {
    int o = n0 + nt * 16 + l15;
    float bias = isQ ? 0.0f : a.b0[o];
    float cs = 0, cs2 = 0;
#pragma unroll
    for (int r = 0; r < 4; r++) {
      float y = acc[nt][r] + bias;
      Out[(m0 + quad * 4 + r) * 256 + o] = y;
      cs += y; cs2 += y * y;
    }
    cs  += __shfl_xor(cs, 16);  cs  += __shfl_xor(cs, 32);
    cs2 += __shfl_xor(cs2, 16); cs2 += __shfl_xor(cs2, 32);
    if (quad == 0) {
      a.ws0s[chunk * 512 + o] = cs;
      a.ws0s[chunk * 512 + 256 + o] = cs2;
    }
  }
}

// Redundant per-block BN0 finalize from D1's slots -> LDS a0/c0.
__device__ __forceinline__ void bn0_finalize(const Args& a, int t, float* sh_a0c0)
{
  int o = t;
  float sumY = 0, cross = 0, SQ2 = 0, SS2 = 0;
#pragma unroll
  for (int b = 0; b < 4; b++) {
    float sq1 = 0, sq2 = 0, ss1 = 0, ss2 = 0;
#pragma unroll
    for (int c = 0; c < 16; c++) {
      sq1 += a.ws0s[(b * 16 + c) * 512 + o];
      sq2 += a.ws0s[(b * 16 + c) * 512 + 256 + o];
    }
#pragma unroll
    for (int c = 0; c < 8; c++) {
      ss1 += a.ws0s[(64 + b * 8 + c) * 512 + o];
      ss2 += a.ws0s[(64 + b * 8 + c) * 512 + 256 + o];
    }
    SQ2 += sq2; SS2 += ss2;
    sumY += 128.0f * sq1 + 256.0f * ss1;
    cross += sq1 * ss1;
  }
  float mean = sumY * INV_N;
  float var = (128.0f * SQ2 + 256.0f * SS2 + 2.0f * cross) * INV_N - mean * mean;
  float aa = a.g0[o] * rsqrtf(var + BN_EPS);
  sh_a0c0[o] = aa;
  sh_a0c0[256 + o] = a.bt0[o] - mean * aa;
}

// Tree barrier, fence-free, contention-minimized. Layout per barrier (u32 idx):
// leaf g at [g*16] (g=0..15, one 64B line each), root at [256], gate g at
// [272+g*16]. Arrival: leaf RMW (<=32 same-line); last-of-leaf bumps root
// (16 RMWs); last-of-root opens all 16 gates. Poll: own gate only (<=32
// pollers/line), check-before-sleep, s_sleep(32) ~ 0.85us backoff.
// __syncthreads drains vmcnt => prior device-scope atomicAdds committed before
// arrival. RELAXED agent-scope everywhere (R16 validated visibility).
__device__ __forceinline__ void grid_barrier(unsigned* base, int bi, int t)
{
  asm volatile("s_waitcnt vmcnt(0)" ::: "memory");
  __syncthreads();
  if (t == 0) {
    int g = bi & 15;
    unsigned old = __hip_atomic_fetch_add(&base[g * 16], 1u,
                     __ATOMIC_RELAXED, __HIP_MEMORY_SCOPE_AGENT);
    if (old == 31u) {
      unsigned r = __hip_atomic_fetch_add(&base[256], 1u,
                     __ATOMIC_RELAXED, __HIP_MEMORY_SCOPE_AGENT);
      if (r == 15u) {
#pragma unroll
        for (int i = 0; i < 16; i++)
          __hip_atomic_store(&base[272 + i * 16], 1u,
                             __ATOMIC_RELAXED, __HIP_MEMORY_SCOPE_AGENT);
      }
    }
    while (__hip_atomic_load(&base[272 + g * 16],
                             __ATOMIC_RELAXED, __HIP_MEMORY_SCOPE_AGENT) == 0u)
      __builtin_amdgcn_s_sleep(32);
  }
  __syncthreads();
}

// ---------------------------------------------------------------------------
// D2: fully fused GEMM1 + BN1 + layer2 + BN2 + out. 512 blocks x 256 thr,
// __launch_bounds__(256,2) => 2 blocks/CU, all co-resident (barrier-safe).
// Per block: one (b,qt,st) tile (16 q x 16 s x 64 j). y1 stays in registers
// as packed bf16 (ku01/ku23), bit-identical to the old stored-y1f path.
// ---------------------------------------------------------------------------
__global__ __launch_bounds__(256, 2) void k_f(Args a)
{
  int bi = blockIdx.x, t = threadIdx.x;
  int w = t >> 6, l = t & 63, l15 = l & 15, quad = l >> 4;
  __shared__ ushort w1f[2048 * 8];    // 32 KB, frag order
  __shared__ float sh_a0c0[512];
  __shared__ float red[2][4][4][16];
  __shared__ float sh_tot[128];
  __shared__ float sh_a1c1[128];
  __shared__ float rs[16], rs2[16];
  __shared__ float sh_fin[2];

  // stage W1 (fp32) -> LDS bf16 frag order
#pragma unroll
  for (int i = 0; i < 8; i++) {
    int fr = i * 256 + t;
    int kk = fr >> 8, r = fr & 255, nt = r >> 6, ln = r & 63;
    const float* src = a.W1 + (nt * 16 + (ln & 15)) * 256 + kk * 32 + (ln >> 4) * 8;
    f32x4 v0 = *(const f32x4*)(src);
    f32x4 v1 = *(const f32x4*)(src + 4);
    frag_u z;
    z.u[0] = pk_bf16(v0[0], v0[1]); z.u[1] = pk_bf16(v0[2], v0[3]);
    z.u[2] = pk_bf16(v1[0], v1[1]); z.u[3] = pk_bf16(v1[2], v1[3]);
    *(s16x8*)(w1f + fr * 8) = z.v;
  }
  bn0_finalize(a, t, sh_a0c0);
  __syncthreads();

  int b_ = bi >> 7, rem = bi & 127, qt = rem >> 3, st = rem & 7;
  const float* asrow = a.As + ((b_ << 7) + st * 16 + l15) * 256;
  const float* aqrow[4];
#pragma unroll
  for (int mt = 0; mt < 4; mt++)
    aqrow[mt] = a.Aq + ((b_ << 8) + qt * 16 + w * 4 + mt) * 256;

  f32x4 acc[4][4] = {};
#pragma unroll
  for (int kk = 0; kk < 8; kk++) {
    int obase = kk * 32 + quad * 8;
    f32x4 a0v0 = *(const f32x4*)(sh_a0c0 + obase);
    f32x4 a0v1 = *(const f32x4*)(sh_a0c0 + obase + 4);
    f32x4 c0v0 = *(const f32x4*)(sh_a0c0 + 256 + obase);
    f32x4 c0v1 = *(const f32x4*)(sh_a0c0 + 256 + obase + 4);
    f32x4 as0 = *(const f32x4*)(asrow + obase);
    f32x4 as1 = *(const f32x4*)(asrow + obase + 4);

    s16x8 zh[4];
#pragma unroll
    for (int mt = 0; mt < 4; mt++) {
      f32x4 aq0 = *(const f32x4*)(aqrow[mt] + obase);
      f32x4 aq1 = *(const f32x4*)(aqrow[mt] + obase + 4);
      f32x4 z0 = (aq0 + as0) * a0v0 + c0v0;
      f32x4 z1 = (aq1 + as1) * a0v1 + c0v1;
      frag_u zz;
      zz.u[0] = pk_bf16(fmaxf(z0[0], 0.0f), fmaxf(z0[1], 0.0f));
      zz.u[1] = pk_bf16(fmaxf(z0[2], 0.0f), fmaxf(z0[3], 0.0f));
      zz.u[2] = pk_bf16(fmaxf(z1[0], 0.0f), fmaxf(z1[1], 0.0f));
      zz.u[3] = pk_bf16(fmaxf(z1[2], 0.0f), fmaxf(z1[3], 0.0f));
      zh[mt] = zz.v;
    }
#pragma unroll
    for (int nt = 0; nt < 4; nt++) {
      s16x8 bw = *(const s16x8*)(w1f + ((kk * 4 + nt) * 64 + l) * 8);
#pragma unroll
      for (int mt = 0; mt < 4; mt++)
        acc[mt][nt] = __builtin_amdgcn_mfma_f32_16x16x32_bf16(zh[mt], bw, acc[mt][nt], 0, 0, 0);
    }
  }

  // epilogue: add bias, bf16-round, KEEP y1 in registers; stats from rounded values
  float biasv[4];
#pragma unroll
  for (int nt = 0; nt < 4; nt++) biasv[nt] = a.b1[nt * 16 + l15];
  unsigned ku01[4][4], ku23[4][4];
  float s[4] = {0, 0, 0, 0}, s2[4] = {0, 0, 0, 0};
#pragma unroll
  for (int mt = 0; mt < 4; mt++) {
#pragma unroll
    for (int nt = 0; nt < 4; nt++) {
      float y0 = acc[mt][nt][0] + biasv[nt];
      float y1 = acc[mt][nt][1] + biasv[nt];
      float y2v = acc[mt][nt][2] + biasv[nt];
      float y3 = acc[mt][nt][3] + biasv[nt];
      unsigned u01 = pk_bf16(y0, y1), u23 = pk_bf16(y2v, y3);
      ku01[mt][nt] = u01; ku23[mt][nt] = u23;
      float f0 = __uint_as_float(u01 << 16), f1 = __uint_as_float(u01 & 0xFFFF0000u);
      float f2 = __uint_as_float(u23 << 16), f3 = __uint_as_float(u23 & 0xFFFF0000u);
      s[nt]  += f0 + f1 + f2 + f3;
      s2[nt] += f0 * f0 + f1 * f1 + f2 * f2 + f3 * f3;
    }
  }
#pragma unroll
  for (int nt = 0; nt < 4; nt++) {
    float v = s[nt], v2 = s2[nt];
    v  += __shfl_xor(v, 16);  v  += __shfl_xor(v, 32);
    v2 += __shfl_xor(v2, 16); v2 += __shfl_xor(v2, 32);
    if (quad == 0) { red[0][w][nt][l15] = v; red[1][w][nt][l15] = v2; }
  }
  __syncthreads();
  if (t < 128) {
    int which = t >> 6, j = t & 63, nt = j >> 4, jl = j & 15;
    float v = red[which][0][nt][jl] + red[which][1][nt][jl] +
              red[which][2][nt][jl] + red[which][3][nt][jl];
    atomicAdd(&a.ws1f[(bi & 15) * 128 + t], v);  // t<64: sum[j], t>=64: sumsq[j]
  }

  // ---- barrier A: BN1 partials visible ----
  grid_barrier(a.cnt, bi, t);

  // BN1 finalize (redundant per block) via cache-bypassing relaxed loads
  if (t < 128) {
    float accv = 0;
#pragma unroll
    for (int c = 0; c < 16; c++)
      accv += __hip_atomic_load(&a.ws1f[c * 128 + t], __ATOMIC_RELAXED, __HIP_MEMORY_SCOPE_AGENT);
    sh_tot[t] = accv;
  }
  __syncthreads();
  if (t < 64) {
    float mean = sh_tot[t] * INV_N;
    float var = sh_tot[64 + t] * INV_N - mean * mean;
    float aa = a.g1[t] * rsqrtf(var + BN_EPS);
    sh_a1c1[t] = aa;
    sh_a1c1[64 + t] = a.bt1[t] - mean * aa;
  }
  __syncthreads();

  // layer 2 from register-held y1: z1 = relu(a1*y1+c1); y2 = z1@W2 + b2
  float a1v[4], c1v[4], w2v[4];
#pragma unroll
  for (int nt = 0; nt < 4; nt++) {
    int j = nt * 16 + l15;
    a1v[nt] = sh_a1c1[j]; c1v[nt] = sh_a1c1[64 + j]; w2v[nt] = a.W2[j];
  }
  float b2v = a.b2[0];
  float y2k[4][4];
  float ls = 0, ls2 = 0;
#pragma unroll
  for (int mt = 0; mt < 4; mt++) {
    float part[4] = {0, 0, 0, 0};
#pragma unroll
    for (int nt = 0; nt < 4; nt++) {
      unsigned u01 = ku01[mt][nt], u23 = ku23[mt][nt];
      float f0 = __uint_as_float(u01 << 16), f1 = __uint_as_float(u01 & 0xFFFF0000u);
      float f2 = __uint_as_float(u23 << 16), f3 = __uint_as_float(u23 & 0xFFFF0000u);
      part[0] += fmaxf(a1v[nt] * f0 + c1v[nt], 0.0f) * w2v[nt];
      part[1] += fmaxf(a1v[nt] * f1 + c1v[nt], 0.0f) * w2v[nt];
      part[2] += fmaxf(a1v[nt] * f2 + c1v[nt], 0.0f) * w2v[nt];
      part[3] += fmaxf(a1v[nt] * f3 + c1v[nt], 0.0f) * w2v[nt];
    }
#pragma unroll
    for (int r = 0; r < 4; r++) {
      float pv = part[r];
      pv += __shfl_xor(pv, 1); pv += __shfl_xor(pv, 2);
      pv += __shfl_xor(pv, 4); pv += __shfl_xor(pv, 8);
      float y = pv + b2v;                    // full sum in all 16 j-lanes
      y2k[mt][r] = y;
      if (l15 == 0) { ls += y; ls2 += y * y; }
    }
  }
  if (l15 == 0) { rs[t >> 4] = ls; rs2[t >> 4] = ls2; }
  __syncthreads();
  if (t == 0) {
    float sv = 0, sv2 = 0;
#pragma unroll
    for (int i = 0; i < 16; i++) { sv += rs[i]; sv2 += rs2[i]; }
    atomicAdd(&a.ws2f[(bi & 15) * 2], sv);       // 32 adds/address, device scope
    atomicAdd(&a.ws2f[(bi & 15) * 2 + 1], sv2);
  }

  // ---- barrier B: BN2 partials visible ----
  grid_barrier(a.cnt + 528, bi, t);

  if (t == 0) {
    float sv = 0, sv2 = 0;
#pragma unroll
    for (int c = 0; c < 16; c++) {
      sv  += __hip_atomic_load(&a.ws2f[c * 2],     __ATOMIC_RELAXED, __HIP_MEMORY_SCOPE_AGENT);
      sv2 += __hip_atomic_load(&a.ws2f[c * 2 + 1], __ATOMIC_RELAXED, __HIP_MEMORY_SCOPE_AGENT);
    }
    float mean = sv * INV_N;
    float var = sv2 * INV_N - mean * mean;
    float aa = a.g2[0] * rsqrtf(var + BN_EPS);
    sh_fin[0] = aa;
    sh_fin[1] = a.bt2[0] - mean * aa;
  }
  __syncthreads();
  float aav = sh_fin[0], ccv = sh_fin[1];

  // BN2 + ReLU on register-held y2; write out at true (b,q,s)
#pragma unroll
  for (int mt = 0; mt < 4; mt++) {
    if (l15 == 0) {
      int q = qt * 16 + w * 4 + mt;
      int P = ((b_ * 256 + q) * 128) + st * 16 + quad * 4;
      f32x4 o;
#pragma unroll
      for (int r = 0; r < 4; r++) o[r] = fmaxf(aav * y2k[mt][r] + ccv, 0.0f);
      *(f32x4*)(a.out + P) = o;
    }
  }
}

extern "C" void kernel_launch(void* const* d_in, const int* in_sizes, int n_in,
                              void* d_out, int out_size, void* d_ws, size_t ws_size,
                              hipStream_t stream)
{
  float* ws = (float*)d_ws;
  Args a;
  a.Sf  = (const float*)d_in[0];   // support [4,128,256]
  a.Qf  = (const float*)d_in[1];   // query   [4,256,256]
  a.W0  = (const float*)d_in[2];   // [256,512]
  a.b0  = (const float*)d_in[3];
  a.g0  = (const float*)d_in[4];
  a.bt0 = (const float*)d_in[5];
  a.W1  = (const float*)d_in[6];   // [64,256]
  a.b1  = (const float*)d_in[7];
  a.g1  = (const float*)d_in[8];
  a.bt1 = (const float*)d_in[9];
  a.W2  = (const float*)d_in[10];  // [1,64]
  a.b2  = (const float*)d_in[11];
  a.g2  = (const float*)d_in[12];
  a.bt2 = (const float*)d_in[13];

  a.Aq   = ws;                       // 262144 f
  a.As   = ws + 262144;              // 131072 f
  a.ws0s = ws + 524288;              // 96*512 = 49152 f (BN0 slots, fully overwritten)
  a.ws1f = ws + 573440;              // 2048 f (16-way spread atomics, zeroed by D1 blk384)
  a.ws2f = ws + 575488;              // 32 f   (16-way spread atomics, zeroed by D1 blk384)
  a.cnt  = (unsigned*)(ws + 575520); // 2x528 u32 barrier areas (zeroed by D1 blk384)
  a.out  = (float*)d_out;            // total ws use ~2.3 MB

  k_g0<<<385, 64, 0, stream>>>(a);
  k_f <<<512, 256, 0, stream>>>(a);
}

// Round 4
// 126.924 us; speedup vs baseline: 1.1218x; 1.0151x over previous
//
#include <hip/hip_runtime.h>
#include <hip/hip_bf16.h>

// RelationNet fused pipeline, fp32 in/out — TWO dispatches.
// B=4 Q=256 S=128 C=256; feats 512 -> 256 -> 64 -> 1; BN (training) + ReLU each layer.
//
// Factorization: concat(uq,us)@W0^T = query@W0a^T + support@W0b^T => Aq[b,q,o], As[b,s,o]
// (b0 folded into As). BN0 stats analytic from per-b sums. GEMM0 ~fp32 via 3-term
// in-register hi/lo bf16 split (D1). BN0 finalize redundant per block in D2.
// R16: D2 = GEMM1 + BN1 + layer2 + BN2 + out fused; y1 register-resident.
// R17: tree barrier (16 leaf lines -> root -> 16 gate lines, s_sleep(32) backoff).
// R18: finalize-once. R17 still had ~33us idle in k_f; dominant op count was the
// REDUNDANT finalizes: BN1 = 512 blocks x 128t x 16 agent-scope loads = 1M fabric
// round-trips bursting onto 128 lines after gate-A. Now the root-finisher BLOCK
// computes a1c1 once and broadcasts via 32 replicas (readers: 128 loads/block,
// <=256 ops/line); BN2 aa/cc ride inside the gate-B lines (3 loads/block).
// BN1 arrival spread widened 16->32 groups (256 RMWs/line). ~16x fewer fabric ops.
// All sync fence-free: per-thread s_waitcnt vmcnt(0) + s_barrier before any signal;
// RELAXED agent-scope atomics only (visibility validated R16/R17 by passing absmax).
// Deadlock-safe: 512 blocks @ __launch_bounds__(256,2), all co-resident; all
// counters/replicas zeroed by D1 blk384 every launch/replay.

typedef __attribute__((ext_vector_type(4))) float f32x4;
typedef __attribute__((ext_vector_type(8))) short s16x8;

#define BN_EPS 1e-5f
#define INV_N  (1.0f/131072.0f)

// cnt-area layout (u32 indices)
#define LEAFA(g)   ((g)*16)          // 16 lines
#define ROOTA      256
#define GATEA(g)   (272 + (g)*16)    // 16 lines
#define REP_A      1024              // 32 replicas x 128 u32 = 1024..5119
#define LEAFB(g)   (5120 + (g)*16)
#define ROOTB      5376
#define GATEB(g)   (5392 + (g)*16)   // per line: [flag, aa2, cc2]
#define CNT_ZERO   5696

__device__ __forceinline__ unsigned pk_bf16(float a, float b) {
  float2 t; t.x = a; t.y = b;
  __hip_bfloat162 h = __float22bfloat162_rn(t);
  return *reinterpret_cast<unsigned*>(&h);  // low16 = bf16(a), high16 = bf16(b)
}
__device__ __forceinline__ void split2(float a, float b, unsigned& uh, unsigned& ul) {
  uh = pk_bf16(a, b);
  float ha = __uint_as_float(uh << 16);
  float hb = __uint_as_float(uh & 0xFFFF0000u);
  ul = pk_bf16(a - ha, b - hb);
}

__device__ __forceinline__ unsigned a_ld(const unsigned* p) {
  return __hip_atomic_load(p, __ATOMIC_RELAXED, __HIP_MEMORY_SCOPE_AGENT);
}
__device__ __forceinline__ float a_ldf(const float* p) {
  return __hip_atomic_load(p, __ATOMIC_RELAXED, __HIP_MEMORY_SCOPE_AGENT);
}
__device__ __forceinline__ void a_st(unsigned* p, unsigned v) {
  __hip_atomic_store(p, v, __ATOMIC_RELAXED, __HIP_MEMORY_SCOPE_AGENT);
}
__device__ __forceinline__ unsigned a_add(unsigned* p) {
  return __hip_atomic_fetch_add(p, 1u, __ATOMIC_RELAXED, __HIP_MEMORY_SCOPE_AGENT);
}

union frag_u { s16x8 v; unsigned u[4]; };

struct Args {
  const float *Sf, *Qf, *W0, *b0, *g0, *bt0, *W1, *b1, *g1, *bt1, *W2, *b2, *g2, *bt2;
  float *Aq, *As, *ws0s, *ws1f, *ws2f, *out;
  unsigned *cnt;
};

// ---------------------------------------------------------------------------
// D1: GEMM0. 385 blocks x 64 thr (one 16x64 wave-tile each). chunk = bi>>2
// (0..63 Aq, 64..95 As), ntile = bi&3. W0 split in-register (3-term).
// BN0 partial slots (no atomics): ws0s[chunk*512 + o] / [..+256+o].
// Block 384: zero ws1f/ws2f atomic pads + the whole cnt area.
// ---------------------------------------------------------------------------
__global__ __launch_bounds__(64) void k_g0(Args a)
{
  int bi = blockIdx.x, t = threadIdx.x;
  if (bi == 384) {
    for (int i = t; i < 4096; i += 64) a.ws1f[i] = 0.0f;
    if (t < 32) a.ws2f[t] = 0.0f;
    for (int i = t; i < CNT_ZERO; i += 64) a.cnt[i] = 0u;
    return;
  }
  int l15 = t & 15, quad = t >> 4;
  int chunk = bi >> 2, ntile = bi & 3;
  bool isQ = (chunk < 64);
  const float* X; float* Out; int m0, koff;
  if (isQ) { m0 = chunk * 16; X = a.Qf; Out = a.Aq; koff = 0; }
  else     { m0 = (chunk - 64) * 16; X = a.Sf; Out = a.As; koff = 256; }
  int n0 = ntile * 64;

  f32x4 acc[4] = {};
#pragma unroll
  for (int ko = 0; ko < 256; ko += 32) {
    const float* row = X + (m0 + l15) * 256 + ko + quad * 8;
    f32x4 v0 = *(const f32x4*)(row);
    f32x4 v1 = *(const f32x4*)(row + 4);
    frag_u ah, al;
#pragma unroll
    for (int j = 0; j < 2; j++) {
      split2(v0[2 * j], v0[2 * j + 1], ah.u[j], al.u[j]);
      split2(v1[2 * j], v1[2 * j + 1], ah.u[2 + j], al.u[2 + j]);
    }
#pragma unroll
    for (int nt = 0; nt < 4; nt++) {
      const float* wrow = a.W0 + (n0 + nt * 16 + l15) * 512 + koff + ko + quad * 8;
      f32x4 w0v = *(const f32x4*)(wrow);
      f32x4 w1v = *(const f32x4*)(wrow + 4);
      frag_u bh, bl;
      split2(w0v[0], w0v[1], bh.u[0], bl.u[0]);
      split2(w0v[2], w0v[3], bh.u[1], bl.u[1]);
      split2(w1v[0], w1v[1], bh.u[2], bl.u[2]);
      split2(w1v[2], w1v[3], bh.u[3], bl.u[3]);
      acc[nt] = __builtin_amdgcn_mfma_f32_16x16x32_bf16(ah.v, bh.v, acc[nt], 0, 0, 0);
      acc[nt] = __builtin_amdgcn_mfma_f32_16x16x32_bf16(al.v, bh.v, acc[nt], 0, 0, 0);
      acc[nt] = __builtin_amdgcn_mfma_f32_16x16x32_bf16(ah.v, bl.v, acc[nt], 0, 0, 0);
    }
  }
  // D: col = l15 (o-in-tile), row = quad*4 + r
#pragma unroll
  for (int nt = 0; nt < 4; nt++) {
    int o = n0 + nt * 16 + l15;
    float bias = isQ ? 0.0f : a.b0[o];
    float cs = 0, cs2 = 0;
#pragma unroll
    for (int r = 0; r < 4; r++) {
      float y = acc[nt][r] + bias;
      Out[(m0 + quad * 4 + r) * 256 + o] = y;
      cs += y; cs2 += y * y;
    }
    cs  += __shfl_xor(cs, 16);  cs  += __shfl_xor(cs, 32);
    cs2 += __shfl_xor(cs2, 16); cs2 += __shfl_xor(cs2, 32);
    if (quad == 0) {
      a.ws0s[chunk * 512 + o] = cs;
      a.ws0s[chunk * 512 + 256 + o] = cs2;
    }
  }
}

// Redundant per-block BN0 finalize from D1's slots -> LDS a0/c0.
__device__ __forceinline__ void bn0_finalize(const Args& a, int t, float* sh_a0c0)
{
  int o = t;
  float sumY = 0, cross = 0, SQ2 = 0, SS2 = 0;
#pragma unroll
  for (int b = 0; b < 4; b++) {
    float sq1 = 0, sq2 = 0, ss1 = 0, ss2 = 0;
#pragma unroll
    for (int c = 0; c < 16; c++) {
      sq1 += a.ws0s[(b * 16 + c) * 512 + o];
      sq2 += a.ws0s[(b * 16 + c) * 512 + 256 + o];
    }
#pragma unroll
    for (int c = 0; c < 8; c++) {
      ss1 += a.ws0s[(64 + b * 8 + c) * 512 + o];
      ss2 += a.ws0s[(64 + b * 8 + c) * 512 + 256 + o];
    }
    SQ2 += sq2; SS2 += ss2;
    sumY += 128.0f * sq1 + 256.0f * ss1;
    cross += sq1 * ss1;
  }
  float mean = sumY * INV_N;
  float var = (128.0f * SQ2 + 256.0f * SS2 + 2.0f * cross) * INV_N - mean * mean;
  float aa = a.g0[o] * rsqrtf(var + BN_EPS);
  sh_a0c0[o] = aa;
  sh_a0c0[256 + o] = a.bt0[o] - mean * aa;
}

// ---------------------------------------------------------------------------
// D2: fully fused GEMM1 + BN1 + layer2 + BN2 + out. 512 blocks x 256 thr,
// __launch_bounds__(256,2) => 2 blocks/CU, all co-resident (barrier-safe).
// Per block: one (b,qt,st) tile (16 q x 16 s x 64 j). y1 stays in registers
// as packed bf16 (ku01/ku23), bit-identical to the old stored-y1f path.
// ---------------------------------------------------------------------------
__global__ __launch_bounds__(256, 2) void k_f(Args a)
{
  int bi = blockIdx.x, t = threadIdx.x;
  int w = t >> 6, l = t & 63, l15 = l & 15, quad = l >> 4;
  __shared__ ushort w1f[2048 * 8];    // 32 KB, frag order
  __shared__ float sh_a0c0[512];
  __shared__ float red[2][4][4][16];
  __shared__ float sh_tot[128];
  __shared__ float sh_a1c1[128];
  __shared__ float rs[16], rs2[16];
  __shared__ float sh_fin[2];
  __shared__ int s_finA;

  // stage W1 (fp32) -> LDS bf16 frag order
#pragma unroll
  for (int i = 0; i < 8; i++) {
    int fr = i * 256 + t;
    int kk = fr >> 8, r = fr & 255, nt = r >> 6, ln = r & 63;
    const float* src = a.W1 + (nt * 16 + (ln & 15)) * 256 + kk * 32 + (ln >> 4) * 8;
    f32x4 v0 = *(const f32x4*)(src);
    f32x4 v1 = *(const f32x4*)(src + 4);
    frag_u z;
    z.u[0] = pk_bf16(v0[0], v0[1]); z.u[1] = pk_bf16(v0[2], v0[3]);
    z.u[2] = pk_bf16(v1[0], v1[1]); z.u[3] = pk_bf16(v1[2], v1[3]);
    *(s16x8*)(w1f + fr * 8) = z.v;
  }
  bn0_finalize(a, t, sh_a0c0);
  __syncthreads();

  int b_ = bi >> 7, rem = bi & 127, qt = rem >> 3, st = rem & 7;
  const float* asrow = a.As + ((b_ << 7) + st * 16 + l15) * 256;
  const float* aqrow[4];
#pragma unroll
  for (int mt = 0; mt < 4; mt++)
    aqrow[mt] = a.Aq + ((b_ << 8) + qt * 16 + w * 4 + mt) * 256;

  f32x4 acc[4][4] = {};
#pragma unroll
  for (int kk = 0; kk < 8; kk++) {
    int obase = kk * 32 + quad * 8;
    f32x4 a0v0 = *(const f32x4*)(sh_a0c0 + obase);
    f32x4 a0v1 = *(const f32x4*)(sh_a0c0 + obase + 4);
    f32x4 c0v0 = *(const f32x4*)(sh_a0c0 + 256 + obase);
    f32x4 c0v1 = *(const f32x4*)(sh_a0c0 + 256 + obase + 4);
    f32x4 as0 = *(const f32x4*)(asrow + obase);
    f32x4 as1 = *(const f32x4*)(asrow + obase + 4);

    s16x8 zh[4];
#pragma unroll
    for (int mt = 0; mt < 4; mt++) {
      f32x4 aq0 = *(const f32x4*)(aqrow[mt] + obase);
      f32x4 aq1 = *(const f32x4*)(aqrow[mt] + obase + 4);
      f32x4 z0 = (aq0 + as0) * a0v0 + c0v0;
      f32x4 z1 = (aq1 + as1) * a0v1 + c0v1;
      frag_u zz;
      zz.u[0] = pk_bf16(fmaxf(z0[0], 0.0f), fmaxf(z0[1], 0.0f));
      zz.u[1] = pk_bf16(fmaxf(z0[2], 0.0f), fmaxf(z0[3], 0.0f));
      zz.u[2] = pk_bf16(fmaxf(z1[0], 0.0f), fmaxf(z1[1], 0.0f));
      zz.u[3] = pk_bf16(fmaxf(z1[2], 0.0f), fmaxf(z1[3], 0.0f));
      zh[mt] = zz.v;
    }
#pragma unroll
    for (int nt = 0; nt < 4; nt++) {
      s16x8 bw = *(const s16x8*)(w1f + ((kk * 4 + nt) * 64 + l) * 8);
#pragma unroll
      for (int mt = 0; mt < 4; mt++)
        acc[mt][nt] = __builtin_amdgcn_mfma_f32_16x16x32_bf16(zh[mt], bw, acc[mt][nt], 0, 0, 0);
    }
  }

  // epilogue: add bias, bf16-round, KEEP y1 in registers; stats from rounded values
  float biasv[4];
#pragma unroll
  for (int nt = 0; nt < 4; nt++) biasv[nt] = a.b1[nt * 16 + l15];
  unsigned ku01[4][4], ku23[4][4];
  float s[4] = {0, 0, 0, 0}, s2[4] = {0, 0, 0, 0};
#pragma unroll
  for (int mt = 0; mt < 4; mt++) {
#pragma unroll
    for (int nt = 0; nt < 4; nt++) {
      float y0 = acc[mt][nt][0] + biasv[nt];
      float y1 = acc[mt][nt][1] + biasv[nt];
      float y2v = acc[mt][nt][2] + biasv[nt];
      float y3 = acc[mt][nt][3] + biasv[nt];
      unsigned u01 = pk_bf16(y0, y1), u23 = pk_bf16(y2v, y3);
      ku01[mt][nt] = u01; ku23[mt][nt] = u23;
      float f0 = __uint_as_float(u01 << 16), f1 = __uint_as_float(u01 & 0xFFFF0000u);
      float f2 = __uint_as_float(u23 << 16), f3 = __uint_as_float(u23 & 0xFFFF0000u);
      s[nt]  += f0 + f1 + f2 + f3;
      s2[nt] += f0 * f0 + f1 * f1 + f2 * f2 + f3 * f3;
    }
  }
#pragma unroll
  for (int nt = 0; nt < 4; nt++) {
    float v = s[nt], v2 = s2[nt];
    v  += __shfl_xor(v, 16);  v  += __shfl_xor(v, 32);
    v2 += __shfl_xor(v2, 16); v2 += __shfl_xor(v2, 32);
    if (quad == 0) { red[0][w][nt][l15] = v; red[1][w][nt][l15] = v2; }
  }
  __syncthreads();
  if (t < 128) {
    int which = t >> 6, j = t & 63, nt = j >> 4, jl = j & 15;
    float v = red[which][0][nt][jl] + red[which][1][nt][jl] +
              red[which][2][nt][jl] + red[which][3][nt][jl];
    atomicAdd(&a.ws1f[(bi & 31) * 128 + t], v);  // 32-group spread: 256 RMWs/line
  }

  // ---- barrier A (tree) + BN1 finalize-once + replica broadcast ----
  asm volatile("s_waitcnt vmcnt(0)" ::: "memory");
  __syncthreads();
  if (t == 0) {
    int g = bi & 15;
    unsigned old = a_add(&a.cnt[LEAFA(g)]);
    int fin = 0;
    if (old == 31u) {
      unsigned r = a_add(&a.cnt[ROOTA]);
      fin = (r == 15u);
    }
    s_finA = fin;
  }
  __syncthreads();
  if (s_finA) {
    // this block alone: finalize BN1 (all 512 arrivals committed before root==15)
    if (t < 128) {
      float accv = 0;
#pragma unroll
      for (int c = 0; c < 32; c++)
        accv += a_ldf(&a.ws1f[c * 128 + t]);
      sh_tot[t] = accv;
    }
    __syncthreads();
    if (t < 64) {
      float mean = sh_tot[t] * INV_N;
      float var = sh_tot[64 + t] * INV_N - mean * mean;
      float aa = a.g1[t] * rsqrtf(var + BN_EPS);
      sh_a1c1[t] = aa;
      sh_a1c1[64 + t] = a.bt1[t] - mean * aa;
    }
    __syncthreads();
    if (t < 128) {
      unsigned uv = __float_as_uint(sh_a1c1[t]);
#pragma unroll
      for (int r = 0; r < 32; r++)
        a_st(&a.cnt[REP_A + r * 128 + t], uv);
    }
    asm volatile("s_waitcnt vmcnt(0)" ::: "memory");
    __syncthreads();
    if (t == 0) {
#pragma unroll
      for (int i = 0; i < 16; i++) a_st(&a.cnt[GATEA(i)], 1u);
    }
  }
  if (t == 0) {
    int g = bi & 15;
    while (a_ld(&a.cnt[GATEA(g)]) == 0u) __builtin_amdgcn_s_sleep(32);
  }
  __syncthreads();
  // read own replica -> sh_a1c1 (uniform for all blocks; finalizer re-reads same bits)
  if (t < 128)
    sh_a1c1[t] = __uint_as_float(a_ld(&a.cnt[REP_A + (bi & 31) * 128 + t]));
  __syncthreads();

  // layer 2 from register-held y1: z1 = relu(a1*y1+c1); y2 = z1@W2 + b2
  float a1v[4], c1v[4], w2v[4];
#pragma unroll
  for (int nt = 0; nt < 4; nt++) {
    int j = nt * 16 + l15;
    a1v[nt] = sh_a1c1[j]; c1v[nt] = sh_a1c1[64 + j]; w2v[nt] = a.W2[j];
  }
  float b2v = a.b2[0];
  float y2k[4][4];
  float ls = 0, ls2 = 0;
#pragma unroll
  for (int mt = 0; mt < 4; mt++) {
    float part[4] = {0, 0, 0, 0};
#pragma unroll
    for (int nt = 0; nt < 4; nt++) {
      unsigned u01 = ku01[mt][nt], u23 = ku23[mt][nt];
      float f0 = __uint_as_float(u01 << 16), f1 = __uint_as_float(u01 & 0xFFFF0000u);
      float f2 = __uint_as_float(u23 << 16), f3 = __uint_as_float(u23 & 0xFFFF0000u);
      part[0] += fmaxf(a1v[nt] * f0 + c1v[nt], 0.0f) * w2v[nt];
      part[1] += fmaxf(a1v[nt] * f1 + c1v[nt], 0.0f) * w2v[nt];
      part[2] += fmaxf(a1v[nt] * f2 + c1v[nt], 0.0f) * w2v[nt];
      part[3] += fmaxf(a1v[nt] * f3 + c1v[nt], 0.0f) * w2v[nt];
    }
#pragma unroll
    for (int r = 0; r < 4; r++) {
      float pv = part[r];
      pv += __shfl_xor(pv, 1); pv += __shfl_xor(pv, 2);
      pv += __shfl_xor(pv, 4); pv += __shfl_xor(pv, 8);
      float y = pv + b2v;                    // full sum in all 16 j-lanes
      y2k[mt][r] = y;
      if (l15 == 0) { ls += y; ls2 += y * y; }
    }
  }
  if (l15 == 0) { rs[t >> 4] = ls; rs2[t >> 4] = ls2; }
  __syncthreads();
  if (t == 0) {
    float sv = 0, sv2 = 0;
#pragma unroll
    for (int i = 0; i < 16; i++) { sv += rs[i]; sv2 += rs2[i]; }
    atomicAdd(&a.ws2f[(bi & 15) * 2], sv);       // 32 adds/address, device scope
    atomicAdd(&a.ws2f[(bi & 15) * 2 + 1], sv2);
  }

  // ---- barrier B (tree): finisher computes BN2 once, result rides the gate lines ----
  asm volatile("s_waitcnt vmcnt(0)" ::: "memory");
  __syncthreads();
  if (t == 0) {
    int g = bi & 15;
    unsigned old = a_add(&a.cnt[LEAFB(g)]);
    if (old == 31u) {
      unsigned r = a_add(&a.cnt[ROOTB]);
      if (r == 15u) {
        float sv = 0, sv2 = 0;
#pragma unroll
        for (int c = 0; c < 16; c++) {
          sv  += a_ldf(&a.ws2f[c * 2]);
          sv2 += a_ldf(&a.ws2f[c * 2 + 1]);
        }
        float mean = sv * INV_N;
        float var = sv2 * INV_N - mean * mean;
        float aa = a.g2[0] * rsqrtf(var + BN_EPS);
        float cc = a.bt2[0] - mean * aa;
        unsigned ua = __float_as_uint(aa), uc = __float_as_uint(cc);
#pragma unroll
        for (int i = 0; i < 16; i++) {
          a_st(&a.cnt[GATEB(i) + 1], ua);
          a_st(&a.cnt[GATEB(i) + 2], uc);
        }
        asm volatile("s_waitcnt vmcnt(0)" ::: "memory");
#pragma unroll
        for (int i = 0; i < 16; i++) a_st(&a.cnt[GATEB(i)], 1u);
      }
    }
    int gg = bi & 15;
    while (a_ld(&a.cnt[GATEB(gg)]) == 0u) __builtin_amdgcn_s_sleep(32);
    sh_fin[0] = __uint_as_float(a_ld(&a.cnt[GATEB(gg) + 1]));
    sh_fin[1] = __uint_as_float(a_ld(&a.cnt[GATEB(gg) + 2]));
  }
  __syncthreads();
  float aav = sh_fin[0], ccv = sh_fin[1];

  // BN2 + ReLU on register-held y2; write out at true (b,q,s)
#pragma unroll
  for (int mt = 0; mt < 4; mt++) {
    if (l15 == 0) {
      int q = qt * 16 + w * 4 + mt;
      int P = ((b_ * 256 + q) * 128) + st * 16 + quad * 4;
      f32x4 o;
#pragma unroll
      for (int r = 0; r < 4; r++) o[r] = fmaxf(aav * y2k[mt][r] + ccv, 0.0f);
      *(f32x4*)(a.out + P) = o;
    }
  }
}

extern "C" void kernel_launch(void* const* d_in, const int* in_sizes, int n_in,
                              void* d_out, int out_size, void* d_ws, size_t ws_size,
                              hipStream_t stream)
{
  float* ws = (float*)d_ws;
  Args a;
  a.Sf  = (const float*)d_in[0];   // support [4,128,256]
  a.Qf  = (const float*)d_in[1];   // query   [4,256,256]
  a.W0  = (const float*)d_in[2];   // [256,512]
  a.b0  = (const float*)d_in[3];
  a.g0  = (const float*)d_in[4];
  a.bt0 = (const float*)d_in[5];
  a.W1  = (const float*)d_in[6];   // [64,256]
  a.b1  = (const float*)d_in[7];
  a.g1  = (const float*)d_in[8];
  a.bt1 = (const float*)d_in[9];
  a.W2  = (const float*)d_in[10];  // [1,64]
  a.b2  = (const float*)d_in[11];
  a.g2  = (const float*)d_in[12];
  a.bt2 = (const float*)d_in[13];

  a.Aq   = ws;                       // 262144 f
  a.As   = ws + 262144;              // 131072 f
  a.ws0s = ws + 524288;              // 96*512 = 49152 f (BN0 slots, fully overwritten)
  a.ws1f = ws + 573440;              // 4096 f (32-way spread atomics, zeroed by D1 blk384)
  a.ws2f = ws + 577536;              // 32 f   (16-way spread atomics, zeroed by D1 blk384)
  a.cnt  = (unsigned*)(ws + 577568); // 5696 u32: trees/gates/replicas (zeroed by D1 blk384)
  a.out  = (float*)d_out;            // total ws use ~2.3 MB

  k_g0<<<385, 64, 0, stream>>>(a);
  k_f <<<512, 256, 0, stream>>>(a);
}

// Round 5
// 125.659 us; speedup vs baseline: 1.1331x; 1.0101x over previous
//
#include <hip/hip_runtime.h>
#include <hip/hip_bf16.h>

// RelationNet fused pipeline, fp32 in/out — TWO dispatches.
// B=4 Q=256 S=128 C=256; feats 512 -> 256 -> 64 -> 1; BN (training) + ReLU each layer.
//
// Factorization: concat(uq,us)@W0^T = query@W0a^T + support@W0b^T => Aq[b,q,o], As[b,s,o]
// (b0 folded into As). BN0 stats analytic from per-b sums. GEMM0 ~fp32 via 3-term
// in-register hi/lo bf16 split (D1). BN0 finalize redundant per block in D2.
// R16: D2 = GEMM1 + BN1 + layer2 + BN2 + out fused; y1 register-resident.
// R17: tree barrier. R18: finalize-once (NULL — agent loads were never the cost).
// R19: zero bulk RMWs. R16-18 all shared 65K agent-scope atomicAdd RMWs for BN1
// partials; RMWs serialize at the coherence point and every block's vmcnt(0) drain
// queues behind them (~30us). Now: per-block DEDICATED slots via relaxed agent
// STORES (fire-and-forget, no sharing), hierarchical aggregation:
//   16-block leaf groups (leaf counter 16 RMWs) -> leaf-finisher sums 16x128 ->
//   root counter (32 RMWs) -> root-finisher sums 32x128, computes a1c1 once,
//   broadcasts 32 replicas, opens 32 gates. BN2 same, payload rides gate lines.
// Total RMWs ~1.1K (vs 65K). Ordering: stores -> vmcnt(0)+s_barrier -> counter RMW
// (RMW serialization proves predecessors' stores acked). RELAXED agent ops only.
// Deadlock-safe: 512 blocks @ __launch_bounds__(256,2), all co-resident; counters
// and gate flags zeroed by D1 blk384 each launch/replay; data slots fully
// overwritten before any read (re-poison safe).

typedef __attribute__((ext_vector_type(4))) float f32x4;
typedef __attribute__((ext_vector_type(8))) short s16x8;

#define BN_EPS 1e-5f
#define INV_N  (1.0f/131072.0f)

// cnt-area layout (u32 indices), one 64B line per counter/gate
#define LEAFA(g)   ((g)*16)           // 32 lines
#define ROOTA      512
#define GATEA(g)   (528 + (g)*16)     // 32 lines
#define LEAFB(g)   (1040 + (g)*16)    // 32 lines
#define ROOTB      1552
#define GATEB(g)   (1568 + (g)*16)    // 32 lines: [flag, aa2, cc2]
#define CNT_ZERO   2080

__device__ __forceinline__ unsigned pk_bf16(float a, float b) {
  float2 t; t.x = a; t.y = b;
  __hip_bfloat162 h = __float22bfloat162_rn(t);
  return *reinterpret_cast<unsigned*>(&h);  // low16 = bf16(a), high16 = bf16(b)
}
__device__ __forceinline__ void split2(float a, float b, unsigned& uh, unsigned& ul) {
  uh = pk_bf16(a, b);
  float ha = __uint_as_float(uh << 16);
  float hb = __uint_as_float(uh & 0xFFFF0000u);
  ul = pk_bf16(a - ha, b - hb);
}

__device__ __forceinline__ unsigned a_ld(const unsigned* p) {
  return __hip_atomic_load(p, __ATOMIC_RELAXED, __HIP_MEMORY_SCOPE_AGENT);
}
__device__ __forceinline__ float a_ldf(const float* p) {
  return __hip_atomic_load(p, __ATOMIC_RELAXED, __HIP_MEMORY_SCOPE_AGENT);
}
__device__ __forceinline__ void a_st(unsigned* p, unsigned v) {
  __hip_atomic_store(p, v, __ATOMIC_RELAXED, __HIP_MEMORY_SCOPE_AGENT);
}
__device__ __forceinline__ void a_stf(float* p, float v) {
  __hip_atomic_store(p, v, __ATOMIC_RELAXED, __HIP_MEMORY_SCOPE_AGENT);
}
__device__ __forceinline__ unsigned a_add(unsigned* p) {
  return __hip_atomic_fetch_add(p, 1u, __ATOMIC_RELAXED, __HIP_MEMORY_SCOPE_AGENT);
}

union frag_u { s16x8 v; unsigned u[4]; };

struct Args {
  const float *Sf, *Qf, *W0, *b0, *g0, *bt0, *W1, *b1, *g1, *bt1, *W2, *b2, *g2, *bt2;
  float *Aq, *As, *ws0s, *ws1p, *ws1g, *ws1r, *ws2p, *ws2g, *out;
  unsigned *cnt;
};

// ---------------------------------------------------------------------------
// D1: GEMM0. 385 blocks x 64 thr (one 16x64 wave-tile each). chunk = bi>>2
// (0..63 Aq, 64..95 As), ntile = bi&3. W0 split in-register (3-term).
// BN0 partial slots (no atomics): ws0s[chunk*512 + o] / [..+256+o].
// Block 384: zero the cnt counters/gates only (data slots are write-before-read).
// ---------------------------------------------------------------------------
__global__ __launch_bounds__(64) void k_g0(Args a)
{
  int bi = blockIdx.x, t = threadIdx.x;
  if (bi == 384) {
    for (int i = t; i < CNT_ZERO; i += 64) a.cnt[i] = 0u;
    return;
  }
  int l15 = t & 15, quad = t >> 4;
  int chunk = bi >> 2, ntile = bi & 3;
  bool isQ = (chunk < 64);
  const float* X; float* Out; int m0, koff;
  if (isQ) { m0 = chunk * 16; X = a.Qf; Out = a.Aq; koff = 0; }
  else     { m0 = (chunk - 64) * 16; X = a.Sf; Out = a.As; koff = 256; }
  int n0 = ntile * 64;

  f32x4 acc[4] = {};
#pragma unroll
  for (int ko = 0; ko < 256; ko += 32) {
    const float* row = X + (m0 + l15) * 256 + ko + quad * 8;
    f32x4 v0 = *(const f32x4*)(row);
    f32x4 v1 = *(const f32x4*)(row + 4);
    frag_u ah, al;
#pragma unroll
    for (int j = 0; j < 2; j++) {
      split2(v0[2 * j], v0[2 * j + 1], ah.u[j], al.u[j]);
      split2(v1[2 * j], v1[2 * j + 1], ah.u[2 + j], al.u[2 + j]);
    }
#pragma unroll
    for (int nt = 0; nt < 4; nt++) {
      const float* wrow = a.W0 + (n0 + nt * 16 + l15) * 512 + koff + ko + quad * 8;
      f32x4 w0v = *(const f32x4*)(wrow);
      f32x4 w1v = *(const f32x4*)(wrow + 4);
      frag_u bh, bl;
      split2(w0v[0], w0v[1], bh.u[0], bl.u[0]);
      split2(w0v[2], w0v[3], bh.u[1], bl.u[1]);
      split2(w1v[0], w1v[1], bh.u[2], bl.u[2]);
      split2(w1v[2], w1v[3], bh.u[3], bl.u[3]);
      acc[nt] = __builtin_amdgcn_mfma_f32_16x16x32_bf16(ah.v, bh.v, acc[nt], 0, 0, 0);
      acc[nt] = __builtin_amdgcn_mfma_f32_16x16x32_bf16(al.v, bh.v, acc[nt], 0, 0, 0);
      acc[nt] = __builtin_amdgcn_mfma_f32_16x16x32_bf16(ah.v, bl.v, acc[nt], 0, 0, 0);
    }
  }
  // D: col = l15 (o-in-tile), row = quad*4 + r
#pragma unroll
  for (int nt = 0; nt < 4; nt++) {
    int o = n0 + nt * 16 + l15;
    float bias = isQ ? 0.0f : a.b0[o];
    float cs = 0, cs2 = 0;
#pragma unroll
    for (int r = 0; r < 4; r++) {
      float y = acc[nt][r] + bias;
      Out[(m0 + quad * 4 + r) * 256 + o] = y;
      cs += y; cs2 += y * y;
    }
    cs  += __shfl_xor(cs, 16);  cs  += __shfl_xor(cs, 32);
    cs2 += __shfl_xor(cs2, 16); cs2 += __shfl_xor(cs2, 32);
    if (quad == 0) {
      a.ws0s[chunk * 512 + o] = cs;
      a.ws0s[chunk * 512 + 256 + o] = cs2;
    }
  }
}

// Redundant per-block BN0 finalize from D1's slots -> LDS a0/c0.
__device__ __forceinline__ void bn0_finalize(const Args& a, int t, float* sh_a0c0)
{
  int o = t;
  float sumY = 0, cross = 0, SQ2 = 0, SS2 = 0;
#pragma unroll
  for (int b = 0; b < 4; b++) {
    float sq1 = 0, sq2 = 0, ss1 = 0, ss2 = 0;
#pragma unroll
    for (int c = 0; c < 16; c++) {
      sq1 += a.ws0s[(b * 16 + c) * 512 + o];
      sq2 += a.ws0s[(b * 16 + c) * 512 + 256 + o];
    }
#pragma unroll
    for (int c = 0; c < 8; c++) {
      ss1 += a.ws0s[(64 + b * 8 + c) * 512 + o];
      ss2 += a.ws0s[(64 + b * 8 + c) * 512 + 256 + o];
    }
    SQ2 += sq2; SS2 += ss2;
    sumY += 128.0f * sq1 + 256.0f * ss1;
    cross += sq1 * ss1;
  }
  float mean = sumY * INV_N;
  float var = (128.0f * SQ2 + 256.0f * SS2 + 2.0f * cross) * INV_N - mean * mean;
  float aa = a.g0[o] * rsqrtf(var + BN_EPS);
  sh_a0c0[o] = aa;
  sh_a0c0[256 + o] = a.bt0[o] - mean * aa;
}

// ---------------------------------------------------------------------------
// D2: fully fused GEMM1 + BN1 + layer2 + BN2 + out. 512 blocks x 256 thr,
// __launch_bounds__(256,2) => 2 blocks/CU, all co-resident (barrier-safe).
// Per block: one (b,qt,st) tile (16 q x 16 s x 64 j). y1 stays in registers
// as packed bf16 (ku01/ku23), bit-identical to the old stored-y1f path.
// ---------------------------------------------------------------------------
__global__ __launch_bounds__(256, 2) void k_f(Args a)
{
  int bi = blockIdx.x, t = threadIdx.x;
  int w = t >> 6, l = t & 63, l15 = l & 15, quad = l >> 4;
  __shared__ ushort w1f[2048 * 8];    // 32 KB, frag order
  __shared__ float sh_a0c0[512];
  __shared__ float red[2][4][4][16];
  __shared__ float sh_tot[128];
  __shared__ float sh_a1c1[128];
  __shared__ float rs[16], rs2[16];
  __shared__ float sh_fin[2];
  __shared__ int s_role;

  // stage W1 (fp32) -> LDS bf16 frag order
#pragma unroll
  for (int i = 0; i < 8; i++) {
    int fr = i * 256 + t;
    int kk = fr >> 8, r = fr & 255, nt = r >> 6, ln = r & 63;
    const float* src = a.W1 + (nt * 16 + (ln & 15)) * 256 + kk * 32 + (ln >> 4) * 8;
    f32x4 v0 = *(const f32x4*)(src);
    f32x4 v1 = *(const f32x4*)(src + 4);
    frag_u z;
    z.u[0] = pk_bf16(v0[0], v0[1]); z.u[1] = pk_bf16(v0[2], v0[3]);
    z.u[2] = pk_bf16(v1[0], v1[1]); z.u[3] = pk_bf16(v1[2], v1[3]);
    *(s16x8*)(w1f + fr * 8) = z.v;
  }
  bn0_finalize(a, t, sh_a0c0);
  __syncthreads();

  int b_ = bi >> 7, rem = bi & 127, qt = rem >> 3, st = rem & 7;
  const float* asrow = a.As + ((b_ << 7) + st * 16 + l15) * 256;
  const float* aqrow[4];
#pragma unroll
  for (int mt = 0; mt < 4; mt++)
    aqrow[mt] = a.Aq + ((b_ << 8) + qt * 16 + w * 4 + mt) * 256;

  f32x4 acc[4][4] = {};
#pragma unroll
  for (int kk = 0; kk < 8; kk++) {
    int obase = kk * 32 + quad * 8;
    f32x4 a0v0 = *(const f32x4*)(sh_a0c0 + obase);
    f32x4 a0v1 = *(const f32x4*)(sh_a0c0 + obase + 4);
    f32x4 c0v0 = *(const f32x4*)(sh_a0c0 + 256 + obase);
    f32x4 c0v1 = *(const f32x4*)(sh_a0c0 + 256 + obase + 4);
    f32x4 as0 = *(const f32x4*)(asrow + obase);
    f32x4 as1 = *(const f32x4*)(asrow + obase + 4);

    s16x8 zh[4];
#pragma unroll
    for (int mt = 0; mt < 4; mt++) {
      f32x4 aq0 = *(const f32x4*)(aqrow[mt] + obase);
      f32x4 aq1 = *(const f32x4*)(aqrow[mt] + obase + 4);
      f32x4 z0 = (aq0 + as0) * a0v0 + c0v0;
      f32x4 z1 = (aq1 + as1) * a0v1 + c0v1;
      frag_u zz;
      zz.u[0] = pk_bf16(fmaxf(z0[0], 0.0f), fmaxf(z0[1], 0.0f));
      zz.u[1] = pk_bf16(fmaxf(z0[2], 0.0f), fmaxf(z0[3], 0.0f));
      zz.u[2] = pk_bf16(fmaxf(z1[0], 0.0f), fmaxf(z1[1], 0.0f));
      zz.u[3] = pk_bf16(fmaxf(z1[2], 0.0f), fmaxf(z1[3], 0.0f));
      zh[mt] = zz.v;
    }
#pragma unroll
    for (int nt = 0; nt < 4; nt++) {
      s16x8 bw = *(const s16x8*)(w1f + ((kk * 4 + nt) * 64 + l) * 8);
#pragma unroll
      for (int mt = 0; mt < 4; mt++)
        acc[mt][nt] = __builtin_amdgcn_mfma_f32_16x16x32_bf16(zh[mt], bw, acc[mt][nt], 0, 0, 0);
    }
  }

  // epilogue: add bias, bf16-round, KEEP y1 in registers; stats from rounded values
  float biasv[4];
#pragma unroll
  for (int nt = 0; nt < 4; nt++) biasv[nt] = a.b1[nt * 16 + l15];
  unsigned ku01[4][4], ku23[4][4];
  float s[4] = {0, 0, 0, 0}, s2[4] = {0, 0, 0, 0};
#pragma unroll
  for (int mt = 0; mt < 4; mt++) {
#pragma unroll
    for (int nt = 0; nt < 4; nt++) {
      float y0 = acc[mt][nt][0] + biasv[nt];
      float y1 = acc[mt][nt][1] + biasv[nt];
      float y2v = acc[mt][nt][2] + biasv[nt];
      float y3 = acc[mt][nt][3] + biasv[nt];
      unsigned u01 = pk_bf16(y0, y1), u23 = pk_bf16(y2v, y3);
      ku01[mt][nt] = u01; ku23[mt][nt] = u23;
      float f0 = __uint_as_float(u01 << 16), f1 = __uint_as_float(u01 & 0xFFFF0000u);
      float f2 = __uint_as_float(u23 << 16), f3 = __uint_as_float(u23 & 0xFFFF0000u);
      s[nt]  += f0 + f1 + f2 + f3;
      s2[nt] += f0 * f0 + f1 * f1 + f2 * f2 + f3 * f3;
    }
  }
#pragma unroll
  for (int nt = 0; nt < 4; nt++) {
    float v = s[nt], v2 = s2[nt];
    v  += __shfl_xor(v, 16);  v  += __shfl_xor(v, 32);
    v2 += __shfl_xor(v2, 16); v2 += __shfl_xor(v2, 32);
    if (quad == 0) { red[0][w][nt][l15] = v; red[1][w][nt][l15] = v2; }
  }
  __syncthreads();
  // BN1 partials -> OWN slot, plain relaxed agent stores (no RMW)
  if (t < 128) {
    int which = t >> 6, j = t & 63, nt = j >> 4, jl = j & 15;
    float v = red[which][0][nt][jl] + red[which][1][nt][jl] +
              red[which][2][nt][jl] + red[which][3][nt][jl];
    a_stf(&a.ws1p[bi * 128 + t], v);   // t<64: sum[j], t>=64: sumsq[j]
  }

  // ---- barrier A: tree arrival + hierarchical BN1 reduce + replica broadcast ----
  asm volatile("s_waitcnt vmcnt(0)" ::: "memory");
  __syncthreads();
  int g = bi & 31;                      // 32 groups x 16 blocks (members g+32c)
  if (t == 0) {
    unsigned old = a_add(&a.cnt[LEAFA(g)]);
    s_role = (old == 15u) ? 1 : 0;
  }
  __syncthreads();
  if (s_role) {
    // leaf-finisher: all 16 group members' stores are committed (RMW order)
    if (t < 128) {
      float sum = 0;
#pragma unroll
      for (int c = 0; c < 16; c++)
        sum += a_ldf(&a.ws1p[(g + c * 32) * 128 + t]);
      a_stf(&a.ws1g[g * 128 + t], sum);
    }
    asm volatile("s_waitcnt vmcnt(0)" ::: "memory");
    __syncthreads();
    if (t == 0) {
      unsigned r = a_add(&a.cnt[ROOTA]);
      s_role = (r == 31u) ? 2 : 1;
    }
    __syncthreads();
    if (s_role == 2) {
      // root-finisher: finalize BN1 once, broadcast 32 replicas, open gates
      if (t < 128) {
        float tot = 0;
#pragma unroll
        for (int gg = 0; gg < 32; gg++)
          tot += a_ldf(&a.ws1g[gg * 128 + t]);
        sh_tot[t] = tot;
      }
      __syncthreads();
      if (t < 64) {
        float mean = sh_tot[t] * INV_N;
        float var = sh_tot[64 + t] * INV_N - mean * mean;
        float aa = a.g1[t] * rsqrtf(var + BN_EPS);
        sh_a1c1[t] = aa;
        sh_a1c1[64 + t] = a.bt1[t] - mean * aa;
      }
      __syncthreads();
      if (t < 128) {
        float uv = sh_a1c1[t];
#pragma unroll
        for (int r2 = 0; r2 < 32; r2++)
          a_stf(&a.ws1r[r2 * 128 + t], uv);
      }
      asm volatile("s_waitcnt vmcnt(0)" ::: "memory");
      __syncthreads();
      if (t == 0) {
#pragma unroll
        for (int i = 0; i < 32; i++) a_st(&a.cnt[GATEA(i)], 1u);
      }
    }
  }
  if (t == 0) {
    while (a_ld(&a.cnt[GATEA(g)]) == 0u) __builtin_amdgcn_s_sleep(32);
  }
  __syncthreads();
  // read own replica (finalizer re-reads identical bits -> uniform across grid)
  if (t < 128)
    sh_a1c1[t] = a_ldf(&a.ws1r[g * 128 + t]);
  __syncthreads();

  // layer 2 from register-held y1: z1 = relu(a1*y1+c1); y2 = z1@W2 + b2
  float a1v[4], c1v[4], w2v[4];
#pragma unroll
  for (int nt = 0; nt < 4; nt++) {
    int j = nt * 16 + l15;
    a1v[nt] = sh_a1c1[j]; c1v[nt] = sh_a1c1[64 + j]; w2v[nt] = a.W2[j];
  }
  float b2v = a.b2[0];
  float y2k[4][4];
  float ls = 0, ls2 = 0;
#pragma unroll
  for (int mt = 0; mt < 4; mt++) {
    float part[4] = {0, 0, 0, 0};
#pragma unroll
    for (int nt = 0; nt < 4; nt++) {
      unsigned u01 = ku01[mt][nt], u23 = ku23[mt][nt];
      float f0 = __uint_as_float(u01 << 16), f1 = __uint_as_float(u01 & 0xFFFF0000u);
      float f2 = __uint_as_float(u23 << 16), f3 = __uint_as_float(u23 & 0xFFFF0000u);
      part[0] += fmaxf(a1v[nt] * f0 + c1v[nt], 0.0f) * w2v[nt];
      part[1] += fmaxf(a1v[nt] * f1 + c1v[nt], 0.0f) * w2v[nt];
      part[2] += fmaxf(a1v[nt] * f2 + c1v[nt], 0.0f) * w2v[nt];
      part[3] += fmaxf(a1v[nt] * f3 + c1v[nt], 0.0f) * w2v[nt];
    }
#pragma unroll
    for (int r = 0; r < 4; r++) {
      float pv = part[r];
      pv += __shfl_xor(pv, 1); pv += __shfl_xor(pv, 2);
      pv += __shfl_xor(pv, 4); pv += __shfl_xor(pv, 8);
      float y = pv + b2v;                    // full sum in all 16 j-lanes
      y2k[mt][r] = y;
      if (l15 == 0) { ls += y; ls2 += y * y; }
    }
  }
  if (l15 == 0) { rs[t >> 4] = ls; rs2[t >> 4] = ls2; }
  __syncthreads();
  // BN2 partials -> OWN 2-float slot (no RMW)
  if (t == 0) {
    float sv = 0, sv2 = 0;
#pragma unroll
    for (int i = 0; i < 16; i++) { sv += rs[i]; sv2 += rs2[i]; }
    a_stf(&a.ws2p[bi * 2], sv);
    a_stf(&a.ws2p[bi * 2 + 1], sv2);
  }

  // ---- barrier B: tree arrival + hierarchical BN2 reduce; payload on gate lines ----
  asm volatile("s_waitcnt vmcnt(0)" ::: "memory");
  __syncthreads();
  if (t == 0) {
    unsigned old = a_add(&a.cnt[LEAFB(g)]);
    if (old == 15u) {
      float s0 = 0, s1 = 0;
#pragma unroll
      for (int c = 0; c < 16; c++) {
        int m = g + c * 32;
        s0 += a_ldf(&a.ws2p[m * 2]);
        s1 += a_ldf(&a.ws2p[m * 2 + 1]);
      }
      a_stf(&a.ws2g[g * 2], s0);
      a_stf(&a.ws2g[g * 2 + 1], s1);
      asm volatile("s_waitcnt vmcnt(0)" ::: "memory");
      unsigned r = a_add(&a.cnt[ROOTB]);
      if (r == 31u) {
        float sv = 0, sv2 = 0;
#pragma unroll
        for (int gg = 0; gg < 32; gg++) {
          sv  += a_ldf(&a.ws2g[gg * 2]);
          sv2 += a_ldf(&a.ws2g[gg * 2 + 1]);
        }
        float mean = sv * INV_N;
        float var = sv2 * INV_N - mean * mean;
        float aa = a.g2[0] * rsqrtf(var + BN_EPS);
        float cc = a.bt2[0] - mean * aa;
        unsigned ua = __float_as_uint(aa), uc = __float_as_uint(cc);
#pragma unroll
        for (int i = 0; i < 32; i++) {
          a_st(&a.cnt[GATEB(i) + 1], ua);
          a_st(&a.cnt[GATEB(i) + 2], uc);
        }
        asm volatile("s_waitcnt vmcnt(0)" ::: "memory");
#pragma unroll
        for (int i = 0; i < 32; i++) a_st(&a.cnt[GATEB(i)], 1u);
      }
    }
    while (a_ld(&a.cnt[GATEB(g)]) == 0u) __builtin_amdgcn_s_sleep(32);
    sh_fin[0] = __uint_as_float(a_ld(&a.cnt[GATEB(g) + 1]));
    sh_fin[1] = __uint_as_float(a_ld(&a.cnt[GATEB(g) + 2]));
  }
  __syncthreads();
  float aav = sh_fin[0], ccv = sh_fin[1];

  // BN2 + ReLU on register-held y2; write out at true (b,q,s)
#pragma unroll
  for (int mt = 0; mt < 4; mt++) {
    if (l15 == 0) {
      int q = qt * 16 + w * 4 + mt;
      int P = ((b_ * 256 + q) * 128) + st * 16 + quad * 4;
      f32x4 o;
#pragma unroll
      for (int r = 0; r < 4; r++) o[r] = fmaxf(aav * y2k[mt][r] + ccv, 0.0f);
      *(f32x4*)(a.out + P) = o;
    }
  }
}

extern "C" void kernel_launch(void* const* d_in, const int* in_sizes, int n_in,
                              void* d_out, int out_size, void* d_ws, size_t ws_size,
                              hipStream_t stream)
{
  float* ws = (float*)d_ws;
  Args a;
  a.Sf  = (const float*)d_in[0];   // support [4,128,256]
  a.Qf  = (const float*)d_in[1];   // query   [4,256,256]
  a.W0  = (const float*)d_in[2];   // [256,512]
  a.b0  = (const float*)d_in[3];
  a.g0  = (const float*)d_in[4];
  a.bt0 = (const float*)d_in[5];
  a.W1  = (const float*)d_in[6];   // [64,256]
  a.b1  = (const float*)d_in[7];
  a.g1  = (const float*)d_in[8];
  a.bt1 = (const float*)d_in[9];
  a.W2  = (const float*)d_in[10];  // [1,64]
  a.b2  = (const float*)d_in[11];
  a.g2  = (const float*)d_in[12];
  a.bt2 = (const float*)d_in[13];

  a.Aq   = ws;                       // 262144 f
  a.As   = ws + 262144;              // 131072 f
  a.ws0s = ws + 524288;              // 96*512 = 49152 f (write-before-read)
  a.ws1p = ws + 573440;              // 512*128 f per-block BN1 partials (w-b-r)
  a.ws1g = ws + 638976;              // 32*128 f group sums (w-b-r)
  a.ws1r = ws + 643072;              // 32*128 f a1c1 replicas (w-b-r)
  a.ws2p = ws + 647168;              // 512*2 f per-block BN2 partials (w-b-r)
  a.ws2g = ws + 648192;              // 32*2 f group sums (w-b-r)
  a.cnt  = (unsigned*)(ws + 648256); // 2080 u32 counters/gates (zeroed by D1 blk384)
  a.out  = (float*)d_out;            // total ws use ~2.6 MB

  k_g0<<<385, 64, 0, stream>>>(a);
  k_f <<<512, 256, 0, stream>>>(a);
}

// Round 6
// 124.255 us; speedup vs baseline: 1.1459x; 1.0113x over previous
//
#include <hip/hip_runtime.h>
#include <hip/hip_bf16.h>

// RelationNet fused pipeline, fp32 in/out — THREE dispatches.
// B=4 Q=256 S=128 C=256; feats 512 -> 256 -> 64 -> 1; BN (training) + ReLU each layer.
//
// Factorization: concat(uq,us)@W0^T = query@W0a^T + support@W0b^T => Aq[b,q,o], As[b,s,o]
// (b0 folded into As). BN0 stats analytic from per-b sums. GEMM0 ~fp32 via 3-term
// in-register hi/lo bf16 split (D1). BN0 finalize redundant per block in D2.
// R16: D2 = GEMM1 + BN1 + layer2 fused; y1 register-resident (bf16-packed).
// R17: tree barrier. R18: finalize-once (NULL). R19: store-slots, no bulk RMW (NULL).
// R20: barrier-B AMPUTATION (ablation with win path). k_f pinned at 41.5us across
// three different barrier mechanisms -> cost is structural latency, not fabric ops.
// Sync-A must stay in-kernel (y1 lives in registers across it); sync-B only needs
// y2 (1 MB) + BN2 partials (4 KB) to cross -> a kernel boundary carries that for
// free. k_f now ends after layer-2 (plain stores of y2 + per-block BN2 partials);
// tiny k_out reduces 1024 partials redundantly per block and streams y2 -> out.
// Deadlock-safe: 512 blocks @ __launch_bounds__(256,2) co-resident for barrier A;
// counters zeroed by D1 blk384 each launch/replay; all data slots write-before-read.

typedef __attribute__((ext_vector_type(4))) float f32x4;
typedef __attribute__((ext_vector_type(8))) short s16x8;

#define BN_EPS 1e-5f
#define INV_N  (1.0f/131072.0f)

// cnt-area layout (u32 indices), one 64B line per counter/gate — barrier A only
#define LEAFA(g)   ((g)*16)           // 32 lines
#define ROOTA      512
#define GATEA(g)   (528 + (g)*16)     // 32 lines
#define CNT_ZERO   1040

__device__ __forceinline__ unsigned pk_bf16(float a, float b) {
  float2 t; t.x = a; t.y = b;
  __hip_bfloat162 h = __float22bfloat162_rn(t);
  return *reinterpret_cast<unsigned*>(&h);  // low16 = bf16(a), high16 = bf16(b)
}
__device__ __forceinline__ void split2(float a, float b, unsigned& uh, unsigned& ul) {
  uh = pk_bf16(a, b);
  float ha = __uint_as_float(uh << 16);
  float hb = __uint_as_float(uh & 0xFFFF0000u);
  ul = pk_bf16(a - ha, b - hb);
}

__device__ __forceinline__ unsigned a_ld(const unsigned* p) {
  return __hip_atomic_load(p, __ATOMIC_RELAXED, __HIP_MEMORY_SCOPE_AGENT);
}
__device__ __forceinline__ float a_ldf(const float* p) {
  return __hip_atomic_load(p, __ATOMIC_RELAXED, __HIP_MEMORY_SCOPE_AGENT);
}
__device__ __forceinline__ void a_st(unsigned* p, unsigned v) {
  __hip_atomic_store(p, v, __ATOMIC_RELAXED, __HIP_MEMORY_SCOPE_AGENT);
}
__device__ __forceinline__ void a_stf(float* p, float v) {
  __hip_atomic_store(p, v, __ATOMIC_RELAXED, __HIP_MEMORY_SCOPE_AGENT);
}
__device__ __forceinline__ unsigned a_add(unsigned* p) {
  return __hip_atomic_fetch_add(p, 1u, __ATOMIC_RELAXED, __HIP_MEMORY_SCOPE_AGENT);
}

union frag_u { s16x8 v; unsigned u[4]; };

struct Args {
  const float *Sf, *Qf, *W0, *b0, *g0, *bt0, *W1, *b1, *g1, *bt1, *W2, *b2, *g2, *bt2;
  float *Aq, *As, *y2, *ws0s, *ws1p, *ws1g, *ws1r, *ws2p, *out;
  unsigned *cnt;
};

// ---------------------------------------------------------------------------
// D1: GEMM0. 385 blocks x 64 thr (one 16x64 wave-tile each). chunk = bi>>2
// (0..63 Aq, 64..95 As), ntile = bi&3. W0 split in-register (3-term).
// BN0 partial slots (no atomics): ws0s[chunk*512 + o] / [..+256+o].
// Block 384: zero barrier-A counters/gates (data slots are write-before-read).
// ---------------------------------------------------------------------------
__global__ __launch_bounds__(64) void k_g0(Args a)
{
  int bi = blockIdx.x, t = threadIdx.x;
  if (bi == 384) {
    for (int i = t; i < CNT_ZERO; i += 64) a.cnt[i] = 0u;
    return;
  }
  int l15 = t & 15, quad = t >> 4;
  int chunk = bi >> 2, ntile = bi & 3;
  bool isQ = (chunk < 64);
  const float* X; float* Out; int m0, koff;
  if (isQ) { m0 = chunk * 16; X = a.Qf; Out = a.Aq; koff = 0; }
  else     { m0 = (chunk - 64) * 16; X = a.Sf; Out = a.As; koff = 256; }
  int n0 = ntile * 64;

  f32x4 acc[4] = {};
#pragma unroll
  for (int ko = 0; ko < 256; ko += 32) {
    const float* row = X + (m0 + l15) * 256 + ko + quad * 8;
    f32x4 v0 = *(const f32x4*)(row);
    f32x4 v1 = *(const f32x4*)(row + 4);
    frag_u ah, al;
#pragma unroll
    for (int j = 0; j < 2; j++) {
      split2(v0[2 * j], v0[2 * j + 1], ah.u[j], al.u[j]);
      split2(v1[2 * j], v1[2 * j + 1], ah.u[2 + j], al.u[2 + j]);
    }
#pragma unroll
    for (int nt = 0; nt < 4; nt++) {
      const float* wrow = a.W0 + (n0 + nt * 16 + l15) * 512 + koff + ko + quad * 8;
      f32x4 w0v = *(const f32x4*)(wrow);
      f32x4 w1v = *(const f32x4*)(wrow + 4);
      frag_u bh, bl;
      split2(w0v[0], w0v[1], bh.u[0], bl.u[0]);
      split2(w0v[2], w0v[3], bh.u[1], bl.u[1]);
      split2(w1v[0], w1v[1], bh.u[2], bl.u[2]);
      split2(w1v[2], w1v[3], bh.u[3], bl.u[3]);
      acc[nt] = __builtin_amdgcn_mfma_f32_16x16x32_bf16(ah.v, bh.v, acc[nt], 0, 0, 0);
      acc[nt] = __builtin_amdgcn_mfma_f32_16x16x32_bf16(al.v, bh.v, acc[nt], 0, 0, 0);
      acc[nt] = __builtin_amdgcn_mfma_f32_16x16x32_bf16(ah.v, bl.v, acc[nt], 0, 0, 0);
    }
  }
  // D: col = l15 (o-in-tile), row = quad*4 + r
#pragma unroll
  for (int nt = 0; nt < 4; nt++) {
    int o = n0 + nt * 16 + l15;
    float bias = isQ ? 0.0f : a.b0[o];
    float cs = 0, cs2 = 0;
#pragma unroll
    for (int r = 0; r < 4; r++) {
      float y = acc[nt][r] + bias;
      Out[(m0 + quad * 4 + r) * 256 + o] = y;
      cs += y; cs2 += y * y;
    }
    cs  += __shfl_xor(cs, 16);  cs  += __shfl_xor(cs, 32);
    cs2 += __shfl_xor(cs2, 16); cs2 += __shfl_xor(cs2, 32);
    if (quad == 0) {
      a.ws0s[chunk * 512 + o] = cs;
      a.ws0s[chunk * 512 + 256 + o] = cs2;
    }
  }
}

// Redundant per-block BN0 finalize from D1's slots -> LDS a0/c0.
__device__ __forceinline__ void bn0_finalize(const Args& a, int t, float* sh_a0c0)
{
  int o = t;
  float sumY = 0, cross = 0, SQ2 = 0, SS2 = 0;
#pragma unroll
  for (int b = 0; b < 4; b++) {
    float sq1 = 0, sq2 = 0, ss1 = 0, ss2 = 0;
#pragma unroll
    for (int c = 0; c < 16; c++) {
      sq1 += a.ws0s[(b * 16 + c) * 512 + o];
      sq2 += a.ws0s[(b * 16 + c) * 512 + 256 + o];
    }
#pragma unroll
    for (int c = 0; c < 8; c++) {
      ss1 += a.ws0s[(64 + b * 8 + c) * 512 + o];
      ss2 += a.ws0s[(64 + b * 8 + c) * 512 + 256 + o];
    }
    SQ2 += sq2; SS2 += ss2;
    sumY += 128.0f * sq1 + 256.0f * ss1;
    cross += sq1 * ss1;
  }
  float mean = sumY * INV_N;
  float var = (128.0f * SQ2 + 256.0f * SS2 + 2.0f * cross) * INV_N - mean * mean;
  float aa = a.g0[o] * rsqrtf(var + BN_EPS);
  sh_a0c0[o] = aa;
  sh_a0c0[256 + o] = a.bt0[o] - mean * aa;
}

// ---------------------------------------------------------------------------
// D2: GEMM1 + BN1(barrier A) + layer2. 512 blocks x 256 thr, launch_bounds
// (256,2) => 2 blocks/CU, all co-resident. Per block: one (b,qt,st) tile.
// y1 stays in registers as packed bf16 across barrier A. Ends by writing y2
// (pre-BN2, true (b,q,s) layout) + per-block BN2 partials with PLAIN stores —
// the kernel boundary provides coherence to D3.
// ---------------------------------------------------------------------------
__global__ __launch_bounds__(256, 2) void k_f(Args a)
{
  int bi = blockIdx.x, t = threadIdx.x;
  int w = t >> 6, l = t & 63, l15 = l & 15, quad = l >> 4;
  __shared__ ushort w1f[2048 * 8];    // 32 KB, frag order
  __shared__ float sh_a0c0[512];
  __shared__ float red[2][4][4][16];
  __shared__ float sh_tot[128];
  __shared__ float sh_a1c1[128];
  __shared__ float rs[16], rs2[16];
  __shared__ int s_role;

  // stage W1 (fp32) -> LDS bf16 frag order
#pragma unroll
  for (int i = 0; i < 8; i++) {
    int fr = i * 256 + t;
    int kk = fr >> 8, r = fr & 255, nt = r >> 6, ln = r & 63;
    const float* src = a.W1 + (nt * 16 + (ln & 15)) * 256 + kk * 32 + (ln >> 4) * 8;
    f32x4 v0 = *(const f32x4*)(src);
    f32x4 v1 = *(const f32x4*)(src + 4);
    frag_u z;
    z.u[0] = pk_bf16(v0[0], v0[1]); z.u[1] = pk_bf16(v0[2], v0[3]);
    z.u[2] = pk_bf16(v1[0], v1[1]); z.u[3] = pk_bf16(v1[2], v1[3]);
    *(s16x8*)(w1f + fr * 8) = z.v;
  }
  bn0_finalize(a, t, sh_a0c0);
  __syncthreads();

  int b_ = bi >> 7, rem = bi & 127, qt = rem >> 3, st = rem & 7;
  const float* asrow = a.As + ((b_ << 7) + st * 16 + l15) * 256;
  const float* aqrow[4];
#pragma unroll
  for (int mt = 0; mt < 4; mt++)
    aqrow[mt] = a.Aq + ((b_ << 8) + qt * 16 + w * 4 + mt) * 256;

  f32x4 acc[4][4] = {};
#pragma unroll
  for (int kk = 0; kk < 8; kk++) {
    int obase = kk * 32 + quad * 8;
    f32x4 a0v0 = *(const f32x4*)(sh_a0c0 + obase);
    f32x4 a0v1 = *(const f32x4*)(sh_a0c0 + obase + 4);
    f32x4 c0v0 = *(const f32x4*)(sh_a0c0 + 256 + obase);
    f32x4 c0v1 = *(const f32x4*)(sh_a0c0 + 256 + obase + 4);
    f32x4 as0 = *(const f32x4*)(asrow + obase);
    f32x4 as1 = *(const f32x4*)(asrow + obase + 4);

    s16x8 zh[4];
#pragma unroll
    for (int mt = 0; mt < 4; mt++) {
      f32x4 aq0 = *(const f32x4*)(aqrow[mt] + obase);
      f32x4 aq1 = *(const f32x4*)(aqrow[mt] + obase + 4);
      f32x4 z0 = (aq0 + as0) * a0v0 + c0v0;
      f32x4 z1 = (aq1 + as1) * a0v1 + c0v1;
      frag_u zz;
      zz.u[0] = pk_bf16(fmaxf(z0[0], 0.0f), fmaxf(z0[1], 0.0f));
      zz.u[1] = pk_bf16(fmaxf(z0[2], 0.0f), fmaxf(z0[3], 0.0f));
      zz.u[2] = pk_bf16(fmaxf(z1[0], 0.0f), fmaxf(z1[1], 0.0f));
      zz.u[3] = pk_bf16(fmaxf(z1[2], 0.0f), fmaxf(z1[3], 0.0f));
      zh[mt] = zz.v;
    }
#pragma unroll
    for (int nt = 0; nt < 4; nt++) {
      s16x8 bw = *(const s16x8*)(w1f + ((kk * 4 + nt) * 64 + l) * 8);
#pragma unroll
      for (int mt = 0; mt < 4; mt++)
        acc[mt][nt] = __builtin_amdgcn_mfma_f32_16x16x32_bf16(zh[mt], bw, acc[mt][nt], 0, 0, 0);
    }
  }

  // epilogue: add bias, bf16-round, KEEP y1 in registers; stats from rounded values
  float biasv[4];
#pragma unroll
  for (int nt = 0; nt < 4; nt++) biasv[nt] = a.b1[nt * 16 + l15];
  unsigned ku01[4][4], ku23[4][4];
  float s[4] = {0, 0, 0, 0}, s2[4] = {0, 0, 0, 0};
#pragma unroll
  for (int mt = 0; mt < 4; mt++) {
#pragma unroll
    for (int nt = 0; nt < 4; nt++) {
      float y0 = acc[mt][nt][0] + biasv[nt];
      float y1 = acc[mt][nt][1] + biasv[nt];
      float y2v = acc[mt][nt][2] + biasv[nt];
      float y3 = acc[mt][nt][3] + biasv[nt];
      unsigned u01 = pk_bf16(y0, y1), u23 = pk_bf16(y2v, y3);
      ku01[mt][nt] = u01; ku23[mt][nt] = u23;
      float f0 = __uint_as_float(u01 << 16), f1 = __uint_as_float(u01 & 0xFFFF0000u);
      float f2 = __uint_as_float(u23 << 16), f3 = __uint_as_float(u23 & 0xFFFF0000u);
      s[nt]  += f0 + f1 + f2 + f3;
      s2[nt] += f0 * f0 + f1 * f1 + f2 * f2 + f3 * f3;
    }
  }
#pragma unroll
  for (int nt = 0; nt < 4; nt++) {
    float v = s[nt], v2 = s2[nt];
    v  += __shfl_xor(v, 16);  v  += __shfl_xor(v, 32);
    v2 += __shfl_xor(v2, 16); v2 += __shfl_xor(v2, 32);
    if (quad == 0) { red[0][w][nt][l15] = v; red[1][w][nt][l15] = v2; }
  }
  __syncthreads();
  // BN1 partials -> OWN slot, plain relaxed agent stores (no RMW)
  if (t < 128) {
    int which = t >> 6, j = t & 63, nt = j >> 4, jl = j & 15;
    float v = red[which][0][nt][jl] + red[which][1][nt][jl] +
              red[which][2][nt][jl] + red[which][3][nt][jl];
    a_stf(&a.ws1p[bi * 128 + t], v);   // t<64: sum[j], t>=64: sumsq[j]
  }

  // ---- barrier A: tree arrival + hierarchical BN1 reduce + replica broadcast ----
  asm volatile("s_waitcnt vmcnt(0)" ::: "memory");
  __syncthreads();
  int g = bi & 31;                      // 32 groups x 16 blocks (members g+32c)
  if (t == 0) {
    unsigned old = a_add(&a.cnt[LEAFA(g)]);
    s_role = (old == 15u) ? 1 : 0;
  }
  __syncthreads();
  if (s_role) {
    // leaf-finisher: all 16 group members' stores are committed (RMW order)
    if (t < 128) {
      float sum = 0;
#pragma unroll
      for (int c = 0; c < 16; c++)
        sum += a_ldf(&a.ws1p[(g + c * 32) * 128 + t]);
      a_stf(&a.ws1g[g * 128 + t], sum);
    }
    asm volatile("s_waitcnt vmcnt(0)" ::: "memory");
    __syncthreads();
    if (t == 0) {
      unsigned r = a_add(&a.cnt[ROOTA]);
      s_role = (r == 31u) ? 2 : 1;
    }
    __syncthreads();
    if (s_role == 2) {
      // root-finisher: finalize BN1 once, broadcast 32 replicas, open gates
      if (t < 128) {
        float tot = 0;
#pragma unroll
        for (int gg = 0; gg < 32; gg++)
          tot += a_ldf(&a.ws1g[gg * 128 + t]);
        sh_tot[t] = tot;
      }
      __syncthreads();
      if (t < 64) {
        float mean = sh_tot[t] * INV_N;
        float var = sh_tot[64 + t] * INV_N - mean * mean;
        float aa = a.g1[t] * rsqrtf(var + BN_EPS);
        sh_a1c1[t] = aa;
        sh_a1c1[64 + t] = a.bt1[t] - mean * aa;
      }
      __syncthreads();
      if (t < 128) {
        float uv = sh_a1c1[t];
#pragma unroll
        for (int r2 = 0; r2 < 32; r2++)
          a_stf(&a.ws1r[r2 * 128 + t], uv);
      }
      asm volatile("s_waitcnt vmcnt(0)" ::: "memory");
      __syncthreads();
      if (t == 0) {
#pragma unroll
        for (int i = 0; i < 32; i++) a_st(&a.cnt[GATEA(i)], 1u);
      }
    }
  }
  if (t == 0) {
    while (a_ld(&a.cnt[GATEA(g)]) == 0u) __builtin_amdgcn_s_sleep(32);
  }
  __syncthreads();
  // read own replica (finalizer re-reads identical bits -> uniform across grid)
  if (t < 128)
    sh_a1c1[t] = a_ldf(&a.ws1r[g * 128 + t]);
  __syncthreads();

  // layer 2 from register-held y1: z1 = relu(a1*y1+c1); y2 = z1@W2 + b2
  float a1v[4], c1v[4], w2v[4];
#pragma unroll
  for (int nt = 0; nt < 4; nt++) {
    int j = nt * 16 + l15;
    a1v[nt] = sh_a1c1[j]; c1v[nt] = sh_a1c1[64 + j]; w2v[nt] = a.W2[j];
  }
  float b2v = a.b2[0];
  float ls = 0, ls2 = 0;
#pragma unroll
  for (int mt = 0; mt < 4; mt++) {
    float part[4] = {0, 0, 0, 0};
#pragma unroll
    for (int nt = 0; nt < 4; nt++) {
      unsigned u01 = ku01[mt][nt], u23 = ku23[mt][nt];
      float f0 = __uint_as_float(u01 << 16), f1 = __uint_as_float(u01 & 0xFFFF0000u);
      float f2 = __uint_as_float(u23 << 16), f3 = __uint_as_float(u23 & 0xFFFF0000u);
      part[0] += fmaxf(a1v[nt] * f0 + c1v[nt], 0.0f) * w2v[nt];
      part[1] += fmaxf(a1v[nt] * f1 + c1v[nt], 0.0f) * w2v[nt];
      part[2] += fmaxf(a1v[nt] * f2 + c1v[nt], 0.0f) * w2v[nt];
      part[3] += fmaxf(a1v[nt] * f3 + c1v[nt], 0.0f) * w2v[nt];
    }
    // butterfly leaves full sum in all 16 j-lanes; write y2 (pre-BN2) to global
    f32x4 o;
#pragma unroll
    for (int r = 0; r < 4; r++) {
      float pv = part[r];
      pv += __shfl_xor(pv, 1); pv += __shfl_xor(pv, 2);
      pv += __shfl_xor(pv, 4); pv += __shfl_xor(pv, 8);
      float y = pv + b2v;
      o[r] = y;
      if (l15 == 0) { ls += y; ls2 += y * y; }
    }
    if (l15 == 0) {
      int q = qt * 16 + w * 4 + mt;
      int P = ((b_ * 256 + q) * 128) + st * 16 + quad * 4;
      *(f32x4*)(a.y2 + P) = o;          // plain store; kernel boundary -> D3
    }
  }
  if (l15 == 0) { rs[t >> 4] = ls; rs2[t >> 4] = ls2; }
  __syncthreads();
  // BN2 partials -> OWN 2-float slot, plain stores (boundary coherence)
  if (t == 0) {
    float sv = 0, sv2 = 0;
#pragma unroll
    for (int i = 0; i < 16; i++) { sv += rs[i]; sv2 += rs2[i]; }
    a.ws2p[bi * 2] = sv;
    a.ws2p[bi * 2 + 1] = sv2;
  }
}

// ---------------------------------------------------------------------------
// D3: BN2 finalize (redundant per block from 1024 plain-stored partials) + out.
// 128 blocks x 256 thr, 4 floats/thread: exactly 131072 outputs.
// ---------------------------------------------------------------------------
__global__ __launch_bounds__(256) void k_out(Args a)
{
  int t = threadIdx.x;
  __shared__ float wsum[4], wsum2[4];
  __shared__ float fin[2];
  // ws2p[t*4 .. t*4+3] = {sum[2t], sumsq[2t], sum[2t+1], sumsq[2t+1]}
  f32x4 v = *(const f32x4*)(a.ws2p + t * 4);
  float s = v[0] + v[2], s2 = v[1] + v[3];
#pragma unroll
  for (int d = 1; d < 64; d <<= 1) { s += __shfl_xor(s, d); s2 += __shfl_xor(s2, d); }
  if ((t & 63) == 0) { wsum[t >> 6] = s; wsum2[t >> 6] = s2; }
  __syncthreads();
  if (t == 0) {
    float sv  = wsum[0] + wsum[1] + wsum[2] + wsum[3];
    float sv2 = wsum2[0] + wsum2[1] + wsum2[2] + wsum2[3];
    float mean = sv * INV_N;
    float var = sv2 * INV_N - mean * mean;
    float aa = a.g2[0] * rsqrtf(var + BN_EPS);
    fin[0] = aa;
    fin[1] = a.bt2[0] - mean * aa;
  }
  __syncthreads();
  float aa = fin[0], cc = fin[1];
  int i = (blockIdx.x * 256 + t) * 4;
  f32x4 y = *(const f32x4*)(a.y2 + i);
  f32x4 o;
#pragma unroll
  for (int r = 0; r < 4; r++) o[r] = fmaxf(aa * y[r] + cc, 0.0f);
  *(f32x4*)(a.out + i) = o;
}

extern "C" void kernel_launch(void* const* d_in, const int* in_sizes, int n_in,
                              void* d_out, int out_size, void* d_ws, size_t ws_size,
                              hipStream_t stream)
{
  float* ws = (float*)d_ws;
  Args a;
  a.Sf  = (const float*)d_in[0];   // support [4,128,256]
  a.Qf  = (const float*)d_in[1];   // query   [4,256,256]
  a.W0  = (const float*)d_in[2];   // [256,512]
  a.b0  = (const float*)d_in[3];
  a.g0  = (const float*)d_in[4];
  a.bt0 = (const float*)d_in[5];
  a.W1  = (const float*)d_in[6];   // [64,256]
  a.b1  = (const float*)d_in[7];
  a.g1  = (const float*)d_in[8];
  a.bt1 = (const float*)d_in[9];
  a.W2  = (const float*)d_in[10];  // [1,64]
  a.b2  = (const float*)d_in[11];
  a.g2  = (const float*)d_in[12];
  a.bt2 = (const float*)d_in[13];

  a.Aq   = ws;                       // 262144 f
  a.As   = ws + 262144;              // 131072 f
  a.y2   = ws + 393216;              // 131072 f (pre-BN2 y2, w-b-r)
  a.ws0s = ws + 524288;              // 96*512 = 49152 f (w-b-r)
  a.ws1p = ws + 573440;              // 512*128 f per-block BN1 partials (w-b-r)
  a.ws1g = ws + 638976;              // 32*128 f group sums (w-b-r)
  a.ws1r = ws + 643072;              // 32*128 f a1c1 replicas (w-b-r)
  a.ws2p = ws + 647168;              // 512*2 f per-block BN2 partials (w-b-r)
  a.cnt  = (unsigned*)(ws + 648192); // 1040 u32 barrier-A counters (zeroed by D1)
  a.out  = (float*)d_out;            // total ws use ~2.6 MB

  k_g0 <<<385, 64, 0, stream>>>(a);
  k_f  <<<512, 256, 0, stream>>>(a);
  k_out<<<128, 256, 0, stream>>>(a);
}